// Round 1
// baseline (9060.975 us; speedup 1.0000x reference)
//
#include <hip/hip_runtime.h>
#include <hip/hip_bf16.h>
#include <math.h>

#define B_ 8192
#define X_ 512
#define H_ 256
#define Z_ 64
#define L_ 16
#define W_ 32
#define G3_ 768

#define STDF 1.0025031276057952f
#define CC 0.9189385332046727f

__device__ __forceinline__ float sigm(float x) { return 1.0f / (1.0f + expf(-x)); }
// log(sigmoid(u)), numerically stable
__device__ __forceinline__ float logsig(float u) {
    return (u > 0.0f) ? -log1pf(expf(-u)) : (u - log1pf(expf(u)));
}

// ---------------- generic tiled f32 GEMM: C = A @ Wt^T + bias, opt ReLU ----
// A: [M, lda] (logical K columns; if extra_mode != 0, logical column K-1 is
//    threshold(extra[row*extra_stride]) instead of A)
// Wt: [N, K] row-major (ldw == K)
// extra_mode: 0 none, 1 (v >= 0.5), 2 (v > 0.5)
#define TM 64
#define TN 64
#define TK 16
__global__ __launch_bounds__(256) void gemm_bias_act(
    const float* __restrict__ A, int lda,
    const float* __restrict__ extra, int extra_stride, int extra_mode,
    const float* __restrict__ Wt,
    const float* __restrict__ bias,
    float* __restrict__ C, int ldc,
    int M, int N, int K, int act)
{
    __shared__ float As[TK][TM];
    __shared__ float Ws[TK][TN];
    const int bm = blockIdx.y * TM;
    const int bn = blockIdx.x * TN;
    const int tid = threadIdx.x;
    const int tc = tid & 15;   // N subgroup
    const int tr = tid >> 4;   // M subgroup
    float acc[4][4] = {};

    for (int k0 = 0; k0 < K; k0 += TK) {
        #pragma unroll
        for (int i = 0; i < 4; ++i) {
            int idx = tid + i * 256;        // 0..1023
            int r   = idx >> 4;             // 0..63
            int kk  = idx & 15;
            int gk  = k0 + kk;
            // A tile
            float va = 0.0f;
            int gr = bm + r;
            if (gk < K) {
                if (extra_mode && gk == K - 1) {
                    float e = extra[gr * extra_stride];
                    va = (extra_mode == 1) ? (e >= 0.5f ? 1.0f : 0.0f)
                                           : (e >  0.5f ? 1.0f : 0.0f);
                } else {
                    va = A[(long)gr * lda + gk];
                }
            }
            As[kk][r] = va;
            // W tile
            float vw = 0.0f;
            int gn = bn + r;
            if (gk < K) vw = Wt[(long)gn * K + gk];
            Ws[kk][r] = vw;
        }
        __syncthreads();
        #pragma unroll
        for (int kk = 0; kk < TK; ++kk) {
            float4 a4 = *reinterpret_cast<const float4*>(&As[kk][tr * 4]);
            float4 w4 = *reinterpret_cast<const float4*>(&Ws[kk][tc * 4]);
            float a[4] = {a4.x, a4.y, a4.z, a4.w};
            float w[4] = {w4.x, w4.y, w4.z, w4.w};
            #pragma unroll
            for (int i = 0; i < 4; ++i)
                #pragma unroll
                for (int j = 0; j < 4; ++j)
                    acc[i][j] = fmaf(a[i], w[j], acc[i][j]);
        }
        __syncthreads();
    }
    #pragma unroll
    for (int i = 0; i < 4; ++i) {
        int r = bm + tr * 4 + i;
        #pragma unroll
        for (int j = 0; j < 4; ++j) {
            int c = bn + tc * 4 + j;
            float v = acc[i][j] + bias[c];
            if (act == 1) v = fmaxf(v, 0.0f);
            C[(long)r * ldc + c] = v;
        }
    }
}

// ---------- out[b*stride] = sigmoid(dot(D[b,:256], w) + b0[0]) -------------
__global__ __launch_bounds__(256) void vec_out_sigmoid(
    const float* __restrict__ D, const float* __restrict__ w,
    const float* __restrict__ b0, float* __restrict__ out, int stride)
{
    int wave = threadIdx.x >> 6;
    int lane = threadIdx.x & 63;
    int b = blockIdx.x * 4 + wave;
    const float* d = D + (long)b * H_;
    float s = 0.0f;
    #pragma unroll
    for (int i = 0; i < 4; ++i) s = fmaf(d[lane + 64 * i], w[lane + 64 * i], s);
    #pragma unroll
    for (int off = 32; off; off >>= 1) s += __shfl_down(s, off);
    if (lane == 0) out[(long)b * stride] = sigm(s + b0[0]);
}

// ---------------- GRU elementwise combine + eps -----------------------------
__global__ __launch_bounds__(256) void gru_combine(
    const float* __restrict__ gi, const float* __restrict__ gh,
    float* __restrict__ z, const float* __restrict__ eps)
{
    int idx = blockIdx.x * 256 + threadIdx.x;   // over B*H
    int b = idx >> 8, h = idx & 255;
    const float* gib = gi + (long)b * G3_;
    const float* ghb = gh + (long)b * G3_;
    float ir = gib[h], iz = gib[H_ + h], in = gib[2 * H_ + h];
    float hr = ghb[h], hz = ghb[H_ + h], hn = ghb[2 * H_ + h];
    float r  = sigm(ir + hr);
    float zt = sigm(iz + hz);
    float n  = tanhf(in + r * hn);
    float zo = z[idx];
    z[idx] = (1.0f - zt) * n + zt * zo + STDF * eps[idx];
}

// ---------------- latent / log_q / log_p_z ---------------------------------
__global__ __launch_bounds__(64) void latent_kernel(
    const float* __restrict__ zfin,
    const float* __restrict__ Wmu, const float* __restrict__ bmu,
    const float* __restrict__ Wlv, const float* __restrict__ blv,
    const float* __restrict__ seps,
    float* __restrict__ latent, float* __restrict__ lq, float* __restrict__ lpz)
{
    __shared__ float zs[H_];
    int b = blockIdx.x, t = threadIdx.x;
    for (int i = t; i < H_; i += 64) zs[i] = zfin[(long)b * H_ + i];
    __syncthreads();
    const float* wm = Wmu + (long)t * H_;
    const float* wl = Wlv + (long)t * H_;
    float smu = bmu[t], slv = blv[t];
    for (int k = 0; k < H_; ++k) {
        smu = fmaf(zs[k], wm[k], smu);
        slv = fmaf(zs[k], wl[k], slv);
    }
    float lv = (slv > 0.0f) ? (slv + log1pf(expf(-slv))) : log1pf(expf(slv));
    float e = seps[(long)b * Z_ + t];
    float lat = smu + expf(0.5f * lv) * e;
    latent[(long)b * Z_ + t] = lat;
    float lpz_c = -CC - 0.5f * lat * lat;
    float d = lat - smu;
    float lq_c = -CC - 0.5f * lv - d * d / (2.0f * expf(lv));
    #pragma unroll
    for (int off = 32; off; off >>= 1) {
        lpz_c += __shfl_down(lpz_c, off);
        lq_c  += __shfl_down(lq_c, off);
    }
    if (t == 0) { lpz[b] = lpz_c; lq[b] = lq_c; }
}

// ---------------- decoder predict heads + BCE accumulation ------------------
__global__ __launch_bounds__(256) void dec_pred_bce(
    const float* __restrict__ D, const float* __restrict__ Wo,  // [32,256]
    const float* __restrict__ bo, const float* __restrict__ workers,
    float* __restrict__ acc, int l)
{
    __shared__ float ds[H_];
    __shared__ float bces[W_];
    int b = blockIdx.x, t = threadIdx.x;
    ds[t] = D[(long)b * H_ + t];
    __syncthreads();
    int w = t >> 3, g = t & 7;
    const float* wo = Wo + (long)w * H_;
    float s = 0.0f;
    for (int i = g; i < H_; i += 8) s = fmaf(ds[i], wo[i], s);
    s += __shfl_down(s, 4, 8);
    s += __shfl_down(s, 2, 8);
    s += __shfl_down(s, 1, 8);
    if (g == 0) {
        float u = s + bo[w];
        float logp   = fmaxf(logsig(u),  -100.0f);
        float log1mp = fmaxf(logsig(-u), -100.0f);
        float wk = workers[((long)w * B_ + b) * L_ + l];
        bces[w] = -(wk * logp + (1.0f - wk) * log1mp);
    }
    __syncthreads();
    if (t < W_) {
        float v = bces[t];
        #pragma unroll
        for (int off = 16; off; off >>= 1) v += __shfl_down(v, off, 32);
        if (t == 0) acc[b] += v;
    }
}

// ---------------- recon + log_p_x -------------------------------------------
__global__ __launch_bounds__(256) void recon_logpx(
    const float* __restrict__ zT, const float* __restrict__ Wr,  // [512,256]
    const float* __restrict__ br, const float* __restrict__ x,
    float* __restrict__ lpx)
{
    __shared__ float zs[H_];
    __shared__ float red[4];
    int b = blockIdx.x, t = threadIdx.x;
    zs[t] = zT[(long)b * H_ + t];
    __syncthreads();
    float total = 0.0f;
    #pragma unroll
    for (int kq = 0; kq < 2; ++kq) {
        int k = t + kq * 256;
        const float* wr = Wr + (long)k * H_;
        float u = br[k];
        for (int i = 0; i < H_; ++i) u = fmaf(zs[i], wr[i], u);
        total = fmaf(x[(long)b * X_ + k], logsig(u), total);
    }
    #pragma unroll
    for (int off = 32; off; off >>= 1) total += __shfl_down(total, off);
    int wave = t >> 6, lane = t & 63;
    if (lane == 0) red[wave] = total;
    __syncthreads();
    if (t == 0) lpx[b] = red[0] + red[1] + red[2] + red[3];
}

// ---------------- KL term ---------------------------------------------------
__global__ __launch_bounds__(256) void kl_kernel(
    const float* __restrict__ tmat, const float* __restrict__ workers,
    float* __restrict__ lkl)
{
    int b = blockIdx.x * 256 + threadIdx.x;
    float wb[L_];
    #pragma unroll
    for (int l = 0; l < L_; ++l) wb[l] = 0.0f;
    for (int w = 0; w < W_; ++w) {
        const float* p = workers + ((long)w * B_ + b) * L_;
        #pragma unroll
        for (int l = 0; l < L_; ++l) wb[l] += p[l];
    }
    float s = 0.0f;
    #pragma unroll
    for (int l = 0; l < L_; ++l) {
        float wbar = wb[l] * (1.0f / 32.0f);
        float tv = tmat[(long)b * L_ + l];
        s += tv * (logf(tv + 1e-6f) - logf(wbar + 1e-6f));
    }
    lkl[b] = s;
}

// ---------------- final reduction ------------------------------------------
__global__ __launch_bounds__(1024) void final_reduce(
    const float* __restrict__ lq, const float* __restrict__ lpz,
    const float* __restrict__ bacc, const float* __restrict__ lpx,
    const float* __restrict__ lkl, float* __restrict__ out)
{
    __shared__ float red[16];
    float s = 0.0f;
    for (int b = threadIdx.x; b < B_; b += 1024)
        s += lq[b] - lpz[b] + bacc[b] - lpx[b] + lkl[b];
    #pragma unroll
    for (int off = 32; off; off >>= 1) s += __shfl_down(s, off);
    int wave = threadIdx.x >> 6, lane = threadIdx.x & 63;
    if (lane == 0) red[wave] = s;
    __syncthreads();
    if (threadIdx.x == 0) {
        float t = 0.0f;
        for (int i = 0; i < 16; ++i) t += red[i];
        out[0] = t / (float)B_;
    }
}

__global__ void zero_kernel(float* __restrict__ p, int n)
{
    int i = blockIdx.x * 256 + threadIdx.x;
    if (i < n) p[i] = 0.0f;
}

extern "C" void kernel_launch(void* const* d_in, const int* in_sizes, int n_in,
                              void* d_out, int out_size, void* d_ws, size_t ws_size,
                              hipStream_t stream)
{
    const float* x       = (const float*)d_in[0];
    const float* workers = (const float*)d_in[1];
    const float* Wf1     = (const float*)d_in[2];
    const float* bf1     = (const float*)d_in[3];
    const float* Wf2     = (const float*)d_in[4];
    const float* bf2     = (const float*)d_in[5];
    const float* eWih    = (const float*)d_in[6];
    const float* eWhh    = (const float*)d_in[7];
    const float* ebih    = (const float*)d_in[8];
    const float* ebhh    = (const float*)d_in[9];
    const float* eWd     = (const float*)d_in[10];
    const float* ebd     = (const float*)d_in[11];
    const float* eWo     = (const float*)d_in[12];
    const float* ebo     = (const float*)d_in[13];
    const float* Wmu     = (const float*)d_in[14];
    const float* bmu     = (const float*)d_in[15];
    const float* Wlv     = (const float*)d_in[16];
    const float* blv     = (const float*)d_in[17];
    const float* dWih    = (const float*)d_in[18];
    const float* dWhh    = (const float*)d_in[19];
    const float* dbih    = (const float*)d_in[20];
    const float* dbhh    = (const float*)d_in[21];
    const float* dWd     = (const float*)d_in[22];
    const float* dbd     = (const float*)d_in[23];
    const float* dWo     = (const float*)d_in[24];
    const float* dbo     = (const float*)d_in[25];
    const float* Wr      = (const float*)d_in[26];
    const float* br      = (const float*)d_in[27];
    const float* enc_eps = (const float*)d_in[28];
    const float* samp_eps= (const float*)d_in[29];
    const float* dec_eps = (const float*)d_in[30];

    float* t    = (float*)d_out;            // [B, L] row-major
    float* loss = t + (long)B_ * L_;        // scalar

    float* ws = (float*)d_ws;
    float* z      = ws;                       // [B,H]
    float* gi     = z + (long)B_ * H_;        // [B,3H]
    float* gh     = gi + (long)B_ * G3_;      // [B,3H]
    float* dbuf   = gh + (long)B_ * G3_;      // [B,H]
    float* latent = dbuf + (long)B_ * H_;     // [B,Z]
    float* lq     = latent + (long)B_ * Z_;   // [B]
    float* lpz    = lq + B_;
    float* lpx    = lpz + B_;
    float* lkl    = lpx + B_;
    float* bacc   = lkl + B_;

    const dim3 blk(256);
    const dim3 gridGI(G3_ / TN, B_ / TM);   // (12, 128)
    const dim3 gridD(H_ / TN, B_ / TM);     // (4, 128)
    const int nBH = B_ * H_;

    // ---- first cell: t[:,0] ----
    zero_kernel<<<(nBH + 255) / 256, blk, 0, stream>>>(z, nBH);
    gemm_bias_act<<<gridD, blk, 0, stream>>>(x, X_, nullptr, 0, 0, Wf1, bf1,
                                             dbuf, H_, B_, H_, X_, 1);
    vec_out_sigmoid<<<B_ / 4, blk, 0, stream>>>(dbuf, Wf2, bf2, t, L_);

    // ---- encoder scan ----
    for (int l = 0; l < L_; ++l) {
        gemm_bias_act<<<gridGI, blk, 0, stream>>>(
            x, X_, t + l, L_, 1,
            eWih + (long)l * G3_ * (X_ + 1), ebih + (long)l * G3_,
            gi, G3_, B_, G3_, X_ + 1, 0);
        gemm_bias_act<<<gridGI, blk, 0, stream>>>(
            z, H_, nullptr, 0, 0,
            eWhh + (long)l * G3_ * H_, ebhh + (long)l * G3_,
            gh, G3_, B_, G3_, H_, 0);
        gru_combine<<<nBH / 256, blk, 0, stream>>>(gi, gh, z,
                                                   enc_eps + (long)l * B_ * H_);
        if (l < L_ - 1) {
            gemm_bias_act<<<gridD, blk, 0, stream>>>(
                z, H_, nullptr, 0, 0,
                eWd + (long)l * H_ * H_, ebd + (long)l * H_,
                dbuf, H_, B_, H_, H_, 1);
            vec_out_sigmoid<<<B_ / 4, blk, 0, stream>>>(
                dbuf, eWo + (long)l * H_, ebo + l, t + (l + 1), L_);
        }
    }

    // ---- latent ----
    latent_kernel<<<B_, 64, 0, stream>>>(z, Wmu, bmu, Wlv, blv, samp_eps,
                                         latent, lq, lpz);

    // ---- decoder scan ----
    zero_kernel<<<(nBH + 255) / 256, blk, 0, stream>>>(z, nBH);
    zero_kernel<<<(B_ + 255) / 256, blk, 0, stream>>>(bacc, B_);
    for (int l = 0; l < L_; ++l) {
        gemm_bias_act<<<gridGI, blk, 0, stream>>>(
            latent, Z_, t + l, L_, 2,
            dWih + (long)l * G3_ * (Z_ + 1), dbih + (long)l * G3_,
            gi, G3_, B_, G3_, Z_ + 1, 0);
        gemm_bias_act<<<gridGI, blk, 0, stream>>>(
            z, H_, nullptr, 0, 0,
            dWhh + (long)l * G3_ * H_, dbhh + (long)l * G3_,
            gh, G3_, B_, G3_, H_, 0);
        gru_combine<<<nBH / 256, blk, 0, stream>>>(gi, gh, z,
                                                   dec_eps + (long)l * B_ * H_);
        gemm_bias_act<<<gridD, blk, 0, stream>>>(
            z, H_, nullptr, 0, 0,
            dWd + (long)l * H_ * H_, dbd + (long)l * H_,
            dbuf, H_, B_, H_, H_, 1);
        dec_pred_bce<<<B_, blk, 0, stream>>>(dbuf, dWo + (long)l * W_ * H_,
                                             dbo + (long)l * W_, workers, bacc, l);
    }

    // ---- recon / log_p_x ----
    recon_logpx<<<B_, blk, 0, stream>>>(z, Wr, br, x, lpx);
    // ---- KL ----
    kl_kernel<<<B_ / 256, blk, 0, stream>>>(t, workers, lkl);
    // ---- final loss ----
    final_reduce<<<1, 1024, 0, stream>>>(lq, lpz, bacc, lpx, lkl, loss);
}

// Round 2
// 2593.730 us; speedup vs baseline: 3.4934x; 3.4934x over previous
//
#include <hip/hip_runtime.h>
#include <hip/hip_bf16.h>
#include <math.h>

#define B_ 8192
#define X_ 512
#define H_ 256
#define Z_ 64
#define L_ 16
#define W_ 32
#define G3_ 768

#define STDF 1.0025031276057952f
#define CC 0.9189385332046727f

typedef _Float16 f16x8 __attribute__((ext_vector_type(8)));
typedef float f32x4 __attribute__((ext_vector_type(4)));

__device__ __forceinline__ float sigm(float x) { return 1.0f / (1.0f + expf(-x)); }
__device__ __forceinline__ float logsig(float u) {
    return (u > 0.0f) ? -log1pf(expf(-u)) : (u - log1pf(expf(u)));
}

#define GLOAD16(gsrc, ldst) \
    __builtin_amdgcn_global_load_lds((const __attribute__((address_space(1))) unsigned int*)(gsrc), \
                                     (__attribute__((address_space(3))) unsigned int*)(ldst), 16, 0, 0)

// ---------------- MFMA f16 GEMM: C = A @ Wt^T + bias (+extra col) (+ReLU) ---
// A: [M, K] f16 row-major. Wt: [N, K] f16 row-major. C: [M, ldc] f32.
// extra_mode: 0 none; 1: += (extra[r*estride] >= .5)*ecol[n]; 2: (> .5).
// BM=128, BK=64, 4 waves (2x2), wave tile 64 x (BN/2).
template<int BN>
__global__ __launch_bounds__(256) void mfma_gemm(
    const _Float16* __restrict__ A,
    const _Float16* __restrict__ Wt,
    const float* __restrict__ bias,
    const float* __restrict__ extra, int estride, int extra_mode,
    const float* __restrict__ ecol,
    float* __restrict__ C, int ldc,
    int K, int act)
{
    constexpr int BM = 128;
    constexpr int BK = 64;
    constexpr int WN = BN / 2;
    constexpr int NFR = WN / 16;
    __shared__ f16x8 lds_v[(BM + BN) * BK / 8];
    char* Asmem = (char*)lds_v;
    char* Wsmem = Asmem + BM * BK * 2;

    const int tid  = threadIdx.x;
    const int wave = tid >> 6;
    const int lane = tid & 63;
    const int wr   = wave >> 1;
    const int wc   = wave & 1;
    const int bm   = blockIdx.y * BM;
    const int bn   = blockIdx.x * BN;
    const int l15  = lane & 15;
    const int l4   = lane >> 4;

    f32x4 acc[4][NFR];
    #pragma unroll
    for (int a = 0; a < 4; ++a)
        #pragma unroll
        for (int b = 0; b < NFR; ++b) {
            f32x4 zz = {0.f, 0.f, 0.f, 0.f};
            acc[a][b] = zz;
        }

    for (int k0 = 0; k0 < K; k0 += BK) {
        // stage A tile: 128 rows x 64 k, XOR-swizzled chunks (c ^= row&7)
        #pragma unroll
        for (int it = 0; it < 4; ++it) {
            int o   = (it * 4 + wave) * 1024 + lane * 16;
            int row = o >> 7;
            int c   = ((o >> 4) & 7) ^ (row & 7);
            const _Float16* src = A + (long)(bm + row) * K + k0 + c * 8;
            GLOAD16(src, Asmem + (it * 4 + wave) * 1024);
        }
        // stage W tile: BN rows x 64 k
        #pragma unroll
        for (int it = 0; it < BN / 32; ++it) {
            int o   = (it * 4 + wave) * 1024 + lane * 16;
            int row = o >> 7;
            int c   = ((o >> 4) & 7) ^ (row & 7);
            const _Float16* src = Wt + (long)(bn + row) * K + k0 + c * 8;
            GLOAD16(src, Wsmem + (it * 4 + wave) * 1024);
        }
        asm volatile("s_waitcnt vmcnt(0)" ::: "memory");
        __syncthreads();
        #pragma unroll
        for (int ks = 0; ks < 2; ++ks) {
            f16x8 af[4], bf[NFR];
            #pragma unroll
            for (int mi = 0; mi < 4; ++mi) {
                int row = wr * 64 + mi * 16 + l15;
                int c   = (ks * 4 + l4) ^ (row & 7);
                af[mi] = *(const f16x8*)(Asmem + row * 128 + c * 16);
            }
            #pragma unroll
            for (int ni = 0; ni < NFR; ++ni) {
                int row = wc * WN + ni * 16 + l15;
                int c   = (ks * 4 + l4) ^ (row & 7);
                bf[ni] = *(const f16x8*)(Wsmem + row * 128 + c * 16);
            }
            #pragma unroll
            for (int mi = 0; mi < 4; ++mi)
                #pragma unroll
                for (int ni = 0; ni < NFR; ++ni)
                    acc[mi][ni] = __builtin_amdgcn_mfma_f32_16x16x32_f16(
                        af[mi], bf[ni], acc[mi][ni], 0, 0, 0);
        }
        __syncthreads();
    }

    #pragma unroll
    for (int mi = 0; mi < 4; ++mi) {
        #pragma unroll
        for (int r = 0; r < 4; ++r) {
            int grow = bm + wr * 64 + mi * 16 + l4 * 4 + r;
            float ext = 0.0f;
            if (extra_mode) {
                float e = extra[(long)grow * estride];
                ext = (extra_mode == 1) ? (e >= 0.5f ? 1.0f : 0.0f)
                                        : (e >  0.5f ? 1.0f : 0.0f);
            }
            #pragma unroll
            for (int ni = 0; ni < NFR; ++ni) {
                int gcol = bn + wc * WN + ni * 16 + l15;
                float v = acc[mi][ni][r] + bias[gcol];
                if (extra_mode) v += ext * ecol[gcol];
                if (act) v = fmaxf(v, 0.0f);
                C[(long)grow * ldc + gcol] = v;
            }
        }
    }
}

// ---------------- f32 -> f16 strided conversion ----------------------------
__global__ __launch_bounds__(256) void conv_f16(
    const float* __restrict__ src, _Float16* __restrict__ dst,
    int Ks, int Kd, long total)
{
    long i = ((long)blockIdx.x * 256 + threadIdx.x) * 8;
    if (i >= total) return;
    long r = i / Kd, k = i - r * Kd;
    const float* s = src + r * Ks + k;
    f16x8 o;
    #pragma unroll
    for (int j = 0; j < 8; ++j) o[j] = (_Float16)s[j];
    *(f16x8*)(dst + i) = o;
}

__global__ __launch_bounds__(256) void extract_col(
    const float* __restrict__ src, float* __restrict__ dst, int Ks, int col, int R)
{
    int i = blockIdx.x * 256 + threadIdx.x;
    if (i < R) dst[i] = src[(long)i * Ks + col];
}

// ---------- out[b*stride] = sigmoid(dot(D[b,:256], w) + b0[0]) -------------
__global__ __launch_bounds__(256) void vec_out_sigmoid(
    const float* __restrict__ D, const float* __restrict__ w,
    const float* __restrict__ b0, float* __restrict__ out, int stride)
{
    int wave = threadIdx.x >> 6;
    int lane = threadIdx.x & 63;
    int b = blockIdx.x * 4 + wave;
    const float* d = D + (long)b * H_;
    float s = 0.0f;
    #pragma unroll
    for (int i = 0; i < 4; ++i) s = fmaf(d[lane + 64 * i], w[lane + 64 * i], s);
    #pragma unroll
    for (int off = 32; off; off >>= 1) s += __shfl_down(s, off);
    if (lane == 0) out[(long)b * stride] = sigm(s + b0[0]);
}

// ---------------- GRU elementwise combine + eps, writes f32 + f16 ----------
__global__ __launch_bounds__(256) void gru_combine(
    const float* __restrict__ gi, const float* __restrict__ gh,
    float* __restrict__ z, _Float16* __restrict__ zh,
    const float* __restrict__ eps)
{
    int idx = blockIdx.x * 256 + threadIdx.x;
    int b = idx >> 8, h = idx & 255;
    const float* gib = gi + (long)b * G3_;
    const float* ghb = gh + (long)b * G3_;
    float ir = gib[h], iz = gib[H_ + h], in = gib[2 * H_ + h];
    float hr = ghb[h], hz = ghb[H_ + h], hn = ghb[2 * H_ + h];
    float r  = sigm(ir + hr);
    float zt = sigm(iz + hz);
    float n  = tanhf(in + r * hn);
    float zo = z[idx];
    float v  = (1.0f - zt) * n + zt * zo + STDF * eps[idx];
    z[idx]  = v;
    zh[idx] = (_Float16)v;
}

__global__ __launch_bounds__(256) void zero2_kernel(
    float* __restrict__ z, _Float16* __restrict__ zh, int n)
{
    int i = blockIdx.x * 256 + threadIdx.x;
    if (i < n) { z[i] = 0.0f; zh[i] = (_Float16)0.0f; }
}

__global__ __launch_bounds__(256) void zero_kernel(float* __restrict__ p, int n)
{
    int i = blockIdx.x * 256 + threadIdx.x;
    if (i < n) p[i] = 0.0f;
}

// ---------------- latent / log_q / log_p_z ---------------------------------
__global__ __launch_bounds__(256) void latent_kernel(
    const float* __restrict__ zfin,
    const float* __restrict__ Wmu, const float* __restrict__ bmu,
    const float* __restrict__ Wlv, const float* __restrict__ blv,
    const float* __restrict__ seps,
    float* __restrict__ latent, _Float16* __restrict__ lath,
    float* __restrict__ lq, float* __restrict__ lpz)
{
    __shared__ float zs[H_];
    __shared__ float redq[4], redp[4];
    int b = blockIdx.x, t = threadIdx.x;
    zs[t] = zfin[(long)b * H_ + t];
    __syncthreads();
    int out = t >> 2, g = t & 3;
    const float* wm = Wmu + (long)out * H_ + g * 64;
    const float* wl = Wlv + (long)out * H_ + g * 64;
    const float* zg = zs + g * 64;
    float smu = 0.0f, slv = 0.0f;
    for (int k = 0; k < 64; ++k) {
        smu = fmaf(zg[k], wm[k], smu);
        slv = fmaf(zg[k], wl[k], slv);
    }
    smu += __shfl_down(smu, 2, 4); smu += __shfl_down(smu, 1, 4);
    slv += __shfl_down(slv, 2, 4); slv += __shfl_down(slv, 1, 4);
    float lpz_c = 0.0f, lq_c = 0.0f;
    if (g == 0) {
        smu += bmu[out]; slv += blv[out];
        float lv = (slv > 0.0f) ? (slv + log1pf(expf(-slv))) : log1pf(expf(slv));
        float e = seps[(long)b * Z_ + out];
        float lat = smu + expf(0.5f * lv) * e;
        latent[(long)b * Z_ + out] = lat;
        lath[(long)b * Z_ + out] = (_Float16)lat;
        lpz_c = -CC - 0.5f * lat * lat;
        float d = lat - smu;
        lq_c = -CC - 0.5f * lv - d * d / (2.0f * expf(lv));
    }
    #pragma unroll
    for (int off = 32; off; off >>= 1) {
        lpz_c += __shfl_down(lpz_c, off);
        lq_c  += __shfl_down(lq_c, off);
    }
    int wv = t >> 6, ln = t & 63;
    if (ln == 0) { redq[wv] = lq_c; redp[wv] = lpz_c; }
    __syncthreads();
    if (t == 0) {
        lq[b]  = redq[0] + redq[1] + redq[2] + redq[3];
        lpz[b] = redp[0] + redp[1] + redp[2] + redp[3];
    }
}

// ---------------- decoder heads + BCE, 32 rows/block ------------------------
__global__ __launch_bounds__(256) void dec_pred_bce(
    const float* __restrict__ D, const float* __restrict__ Wo,
    const float* __restrict__ bo, const float* __restrict__ workers,
    float* __restrict__ acc, int l)
{
    __shared__ float ds[32][257];
    __shared__ float part[8][32];
    int tid = threadIdx.x;
    int b0 = blockIdx.x * 32;
    for (int i = 0; i < 32; ++i) {
        int idx = tid + i * 256;
        int r = idx >> 8, cc = idx & 255;
        ds[r][cc] = D[(long)(b0 + r) * H_ + cc];
    }
    __syncthreads();
    int r = tid & 31;
    int g = tid >> 5;            // 0..7, 4 workers each
    const float* w0 = Wo + (long)(g * 4 + 0) * H_;
    const float* w1 = Wo + (long)(g * 4 + 1) * H_;
    const float* w2 = Wo + (long)(g * 4 + 2) * H_;
    const float* w3 = Wo + (long)(g * 4 + 3) * H_;
    float s0 = 0.f, s1 = 0.f, s2 = 0.f, s3 = 0.f;
    for (int i = 0; i < H_; ++i) {
        float d = ds[r][i];
        s0 = fmaf(d, w0[i], s0);
        s1 = fmaf(d, w1[i], s1);
        s2 = fmaf(d, w2[i], s2);
        s3 = fmaf(d, w3[i], s3);
    }
    int b = b0 + r;
    float sv[4] = {s0, s1, s2, s3};
    float tot = 0.0f;
    #pragma unroll
    for (int j = 0; j < 4; ++j) {
        int w = g * 4 + j;
        float u = sv[j] + bo[w];
        float logp   = fmaxf(logsig(u),  -100.0f);
        float log1mp = fmaxf(logsig(-u), -100.0f);
        float wk = workers[((long)w * B_ + b) * L_ + l];
        tot += -(wk * logp + (1.0f - wk) * log1mp);
    }
    part[g][r] = tot;
    __syncthreads();
    if (tid < 32) {
        float t2 = 0.0f;
        #pragma unroll
        for (int g2 = 0; g2 < 8; ++g2) t2 += part[g2][tid];
        acc[b0 + tid] += t2;
    }
}

// ---------------- log_p_x from u = logits ----------------------------------
__global__ __launch_bounds__(256) void logpx_reduce(
    const float* __restrict__ u, const float* __restrict__ x,
    float* __restrict__ lpx)
{
    int wave = threadIdx.x >> 6, lane = threadIdx.x & 63;
    int b = blockIdx.x * 4 + wave;
    const float* ub = u + (long)b * X_;
    const float* xb = x + (long)b * X_;
    float s = 0.0f;
    #pragma unroll
    for (int i = 0; i < 8; ++i) {
        int k = lane + i * 64;
        s = fmaf(xb[k], logsig(ub[k]), s);
    }
    #pragma unroll
    for (int off = 32; off; off >>= 1) s += __shfl_down(s, off);
    if (lane == 0) lpx[b] = s;
}

// ---------------- KL term ---------------------------------------------------
__global__ __launch_bounds__(256) void kl_kernel(
    const float* __restrict__ tmat, const float* __restrict__ workers,
    float* __restrict__ lkl)
{
    int b = blockIdx.x * 256 + threadIdx.x;
    float wb[L_];
    #pragma unroll
    for (int l = 0; l < L_; ++l) wb[l] = 0.0f;
    for (int w = 0; w < W_; ++w) {
        const float* p = workers + ((long)w * B_ + b) * L_;
        #pragma unroll
        for (int l = 0; l < L_; ++l) wb[l] += p[l];
    }
    float s = 0.0f;
    #pragma unroll
    for (int l = 0; l < L_; ++l) {
        float wbar = wb[l] * (1.0f / 32.0f);
        float tv = tmat[(long)b * L_ + l];
        s += tv * (logf(tv + 1e-6f) - logf(wbar + 1e-6f));
    }
    lkl[b] = s;
}

// ---------------- final reduction ------------------------------------------
__global__ __launch_bounds__(1024) void final_reduce(
    const float* __restrict__ lq, const float* __restrict__ lpz,
    const float* __restrict__ bacc, const float* __restrict__ lpx,
    const float* __restrict__ lkl, float* __restrict__ out)
{
    __shared__ float red[16];
    float s = 0.0f;
    for (int b = threadIdx.x; b < B_; b += 1024)
        s += lq[b] - lpz[b] + bacc[b] - lpx[b] + lkl[b];
    #pragma unroll
    for (int off = 32; off; off >>= 1) s += __shfl_down(s, off);
    int wave = threadIdx.x >> 6, lane = threadIdx.x & 63;
    if (lane == 0) red[wave] = s;
    __syncthreads();
    if (threadIdx.x == 0) {
        float t = 0.0f;
        for (int i = 0; i < 16; ++i) t += red[i];
        out[0] = t / (float)B_;
    }
}

extern "C" void kernel_launch(void* const* d_in, const int* in_sizes, int n_in,
                              void* d_out, int out_size, void* d_ws, size_t ws_size,
                              hipStream_t stream)
{
    const float* x       = (const float*)d_in[0];
    const float* workers = (const float*)d_in[1];
    const float* Wf1     = (const float*)d_in[2];
    const float* bf1     = (const float*)d_in[3];
    const float* Wf2     = (const float*)d_in[4];
    const float* bf2     = (const float*)d_in[5];
    const float* eWih    = (const float*)d_in[6];
    const float* eWhh    = (const float*)d_in[7];
    const float* ebih    = (const float*)d_in[8];
    const float* ebhh    = (const float*)d_in[9];
    const float* eWd     = (const float*)d_in[10];
    const float* ebd     = (const float*)d_in[11];
    const float* eWo     = (const float*)d_in[12];
    const float* ebo     = (const float*)d_in[13];
    const float* Wmu     = (const float*)d_in[14];
    const float* bmu     = (const float*)d_in[15];
    const float* Wlv     = (const float*)d_in[16];
    const float* blv     = (const float*)d_in[17];
    const float* dWih    = (const float*)d_in[18];
    const float* dWhh    = (const float*)d_in[19];
    const float* dbih    = (const float*)d_in[20];
    const float* dbhh    = (const float*)d_in[21];
    const float* dWd     = (const float*)d_in[22];
    const float* dbd     = (const float*)d_in[23];
    const float* dWo     = (const float*)d_in[24];
    const float* dbo     = (const float*)d_in[25];
    const float* Wr      = (const float*)d_in[26];
    const float* br      = (const float*)d_in[27];
    const float* enc_eps = (const float*)d_in[28];
    const float* samp_eps= (const float*)d_in[29];
    const float* dec_eps = (const float*)d_in[30];

    float* t    = (float*)d_out;
    float* loss = t + (long)B_ * L_;

    char* p = (char*)d_ws;
    auto alloc = [&](size_t bytes) {
        char* r = p;
        p += (bytes + 255) & ~(size_t)255;
        return r;
    };
    _Float16* xh    = (_Float16*)alloc((size_t)B_ * X_ * 2);
    _Float16* zh    = (_Float16*)alloc((size_t)B_ * H_ * 2);
    _Float16* lath  = (_Float16*)alloc((size_t)B_ * Z_ * 2);
    _Float16* Wf1h  = (_Float16*)alloc((size_t)H_ * X_ * 2);
    _Float16* eWihh = (_Float16*)alloc((size_t)L_ * G3_ * X_ * 2);
    _Float16* eWhhh = (_Float16*)alloc((size_t)L_ * G3_ * H_ * 2);
    _Float16* eWdh  = (_Float16*)alloc((size_t)L_ * H_ * H_ * 2);
    _Float16* dWihh = (_Float16*)alloc((size_t)L_ * G3_ * Z_ * 2);
    _Float16* dWhhh = (_Float16*)alloc((size_t)L_ * G3_ * H_ * 2);
    _Float16* dWdh  = (_Float16*)alloc((size_t)L_ * H_ * H_ * 2);
    _Float16* Wrh   = (_Float16*)alloc((size_t)X_ * H_ * 2);
    float* eWihc  = (float*)alloc((size_t)L_ * G3_ * 4);
    float* dWihc  = (float*)alloc((size_t)L_ * G3_ * 4);
    float* z      = (float*)alloc((size_t)B_ * H_ * 4);
    float* gi     = (float*)alloc((size_t)B_ * G3_ * 4);   // also recon logits
    float* gh     = (float*)alloc((size_t)B_ * G3_ * 4);
    float* dbuf   = (float*)alloc((size_t)B_ * H_ * 4);
    float* latent = (float*)alloc((size_t)B_ * Z_ * 4);
    float* lq     = (float*)alloc((size_t)B_ * 4);
    float* lpz    = (float*)alloc((size_t)B_ * 4);
    float* lpx    = (float*)alloc((size_t)B_ * 4);
    float* lkl    = (float*)alloc((size_t)B_ * 4);
    float* bacc   = (float*)alloc((size_t)B_ * 4);

    const dim3 blk(256);
    const int nBH = B_ * H_;
    auto cgrid = [](long total) { return dim3((unsigned)((total / 8 + 255) / 256)); };

    // ---- weight/activation conversions to f16 ----
    conv_f16<<<cgrid((long)B_ * X_), blk, 0, stream>>>(x, xh, X_, X_, (long)B_ * X_);
    conv_f16<<<cgrid((long)H_ * X_), blk, 0, stream>>>(Wf1, Wf1h, X_, X_, (long)H_ * X_);
    conv_f16<<<cgrid((long)L_ * G3_ * X_), blk, 0, stream>>>(eWih, eWihh, X_ + 1, X_, (long)L_ * G3_ * X_);
    conv_f16<<<cgrid((long)L_ * G3_ * H_), blk, 0, stream>>>(eWhh, eWhhh, H_, H_, (long)L_ * G3_ * H_);
    conv_f16<<<cgrid((long)L_ * H_ * H_), blk, 0, stream>>>(eWd, eWdh, H_, H_, (long)L_ * H_ * H_);
    conv_f16<<<cgrid((long)L_ * G3_ * Z_), blk, 0, stream>>>(dWih, dWihh, Z_ + 1, Z_, (long)L_ * G3_ * Z_);
    conv_f16<<<cgrid((long)L_ * G3_ * H_), blk, 0, stream>>>(dWhh, dWhhh, H_, H_, (long)L_ * G3_ * H_);
    conv_f16<<<cgrid((long)L_ * H_ * H_), blk, 0, stream>>>(dWd, dWdh, H_, H_, (long)L_ * H_ * H_);
    conv_f16<<<cgrid((long)X_ * H_), blk, 0, stream>>>(Wr, Wrh, H_, H_, (long)X_ * H_);
    extract_col<<<(L_ * G3_ + 255) / 256, blk, 0, stream>>>(eWih, eWihc, X_ + 1, X_, L_ * G3_);
    extract_col<<<(L_ * G3_ + 255) / 256, blk, 0, stream>>>(dWih, dWihc, Z_ + 1, Z_, L_ * G3_);

    // ---- first cell: t[:,0] ----
    zero2_kernel<<<(nBH + 255) / 256, blk, 0, stream>>>(z, zh, nBH);
    mfma_gemm<64><<<dim3(H_ / 64, B_ / 128), blk, 0, stream>>>(
        xh, Wf1h, bf1, nullptr, 0, 0, nullptr, dbuf, H_, X_, 1);
    vec_out_sigmoid<<<B_ / 4, blk, 0, stream>>>(dbuf, Wf2, bf2, t, L_);

    // ---- encoder scan ----
    for (int l = 0; l < L_; ++l) {
        mfma_gemm<128><<<dim3(G3_ / 128, B_ / 128), blk, 0, stream>>>(
            xh, eWihh + (long)l * G3_ * X_, ebih + (long)l * G3_,
            t + l, L_, 1, eWihc + (long)l * G3_, gi, G3_, X_, 0);
        mfma_gemm<128><<<dim3(G3_ / 128, B_ / 128), blk, 0, stream>>>(
            zh, eWhhh + (long)l * G3_ * H_, ebhh + (long)l * G3_,
            nullptr, 0, 0, nullptr, gh, G3_, H_, 0);
        gru_combine<<<nBH / 256, blk, 0, stream>>>(gi, gh, z, zh,
                                                   enc_eps + (long)l * B_ * H_);
        if (l < L_ - 1) {
            mfma_gemm<64><<<dim3(H_ / 64, B_ / 128), blk, 0, stream>>>(
                zh, eWdh + (long)l * H_ * H_, ebd + (long)l * H_,
                nullptr, 0, 0, nullptr, dbuf, H_, H_, 1);
            vec_out_sigmoid<<<B_ / 4, blk, 0, stream>>>(
                dbuf, eWo + (long)l * H_, ebo + l, t + (l + 1), L_);
        }
    }

    // ---- latent ----
    latent_kernel<<<B_, blk, 0, stream>>>(z, Wmu, bmu, Wlv, blv, samp_eps,
                                          latent, lath, lq, lpz);

    // ---- decoder scan ----
    zero2_kernel<<<(nBH + 255) / 256, blk, 0, stream>>>(z, zh, nBH);
    zero_kernel<<<(B_ + 255) / 256, blk, 0, stream>>>(bacc, B_);
    for (int l = 0; l < L_; ++l) {
        mfma_gemm<128><<<dim3(G3_ / 128, B_ / 128), blk, 0, stream>>>(
            lath, dWihh + (long)l * G3_ * Z_, dbih + (long)l * G3_,
            t + l, L_, 2, dWihc + (long)l * G3_, gi, G3_, Z_, 0);
        mfma_gemm<128><<<dim3(G3_ / 128, B_ / 128), blk, 0, stream>>>(
            zh, dWhhh + (long)l * G3_ * H_, dbhh + (long)l * G3_,
            nullptr, 0, 0, nullptr, gh, G3_, H_, 0);
        gru_combine<<<nBH / 256, blk, 0, stream>>>(gi, gh, z, zh,
                                                   dec_eps + (long)l * B_ * H_);
        mfma_gemm<64><<<dim3(H_ / 64, B_ / 128), blk, 0, stream>>>(
            zh, dWdh + (long)l * H_ * H_, dbd + (long)l * H_,
            nullptr, 0, 0, nullptr, dbuf, H_, H_, 1);
        dec_pred_bce<<<B_ / 32, blk, 0, stream>>>(dbuf, dWo + (long)l * W_ * H_,
                                                  dbo + (long)l * W_, workers, bacc, l);
    }

    // ---- recon logits -> log_p_x ----
    mfma_gemm<128><<<dim3(X_ / 128, B_ / 128), blk, 0, stream>>>(
        zh, Wrh, br, nullptr, 0, 0, nullptr, gi, X_, H_, 0);
    logpx_reduce<<<B_ / 4, blk, 0, stream>>>(gi, x, lpx);
    // ---- KL ----
    kl_kernel<<<B_ / 256, blk, 0, stream>>>(t, workers, lkl);
    // ---- final loss ----
    final_reduce<<<1, 1024, 0, stream>>>(lq, lpz, bacc, lpx, lkl, loss);
}

// Round 3
// 2050.527 us; speedup vs baseline: 4.4189x; 1.2649x over previous
//
#include <hip/hip_runtime.h>
#include <hip/hip_bf16.h>
#include <math.h>

#define B_ 8192
#define X_ 512
#define H_ 256
#define Z_ 64
#define L_ 16
#define W_ 32
#define G3_ 768

#define STDF 1.0025031276057952f
#define CC 0.9189385332046727f

typedef _Float16 f16x8 __attribute__((ext_vector_type(8)));
typedef float f32x4 __attribute__((ext_vector_type(4)));

__device__ __forceinline__ float sigm(float x) { return 1.0f / (1.0f + expf(-x)); }
__device__ __forceinline__ float logsig(float u) {
    return (u > 0.0f) ? -log1pf(expf(-u)) : (u - log1pf(expf(u)));
}

#define GLOAD16(gsrc, ldst) \
    __builtin_amdgcn_global_load_lds((const __attribute__((address_space(1))) unsigned int*)(gsrc), \
                                     (__attribute__((address_space(3))) unsigned int*)(ldst), 16, 0, 0)

// ---------------- generic MFMA f16 GEMM (f32 out) ---------------------------
// A: [M,K] f16. Wt: [N,K] f16. C: [M,ldc] f32. BM=128, BK=64, 4 waves 2x2.
template<int BN>
__global__ __launch_bounds__(256) void mfma_gemm(
    const _Float16* __restrict__ A,
    const _Float16* __restrict__ Wt,
    const float* __restrict__ bias,
    float* __restrict__ C, int ldc,
    int K, int act)
{
    constexpr int BM = 128;
    constexpr int WN = BN / 2;
    constexpr int NFR = WN / 16;
    __shared__ char smem[(BM + BN) * 128];
    char* Asmem = smem;
    char* Wsmem = smem + BM * 128;

    const int tid  = threadIdx.x;
    const int wave = tid >> 6;
    const int lane = tid & 63;
    const int wr   = wave >> 1;
    const int wc   = wave & 1;
    const int bm   = blockIdx.y * BM;
    const int bn   = blockIdx.x * BN;
    const int l15  = lane & 15;
    const int l4   = lane >> 4;

    f32x4 acc[4][NFR];
    #pragma unroll
    for (int a = 0; a < 4; ++a)
        #pragma unroll
        for (int b = 0; b < NFR; ++b) {
            f32x4 zz = {0.f, 0.f, 0.f, 0.f};
            acc[a][b] = zz;
        }

    for (int k0 = 0; k0 < K; k0 += 64) {
        #pragma unroll
        for (int it = 0; it < 4; ++it) {
            int o   = (it * 4 + wave) * 1024 + lane * 16;
            int row = o >> 7;
            int c   = ((o >> 4) & 7) ^ (row & 7);
            GLOAD16(A + (long)(bm + row) * K + k0 + c * 8, Asmem + (it * 4 + wave) * 1024);
        }
        #pragma unroll
        for (int it = 0; it < BN / 32; ++it) {
            int o   = (it * 4 + wave) * 1024 + lane * 16;
            int row = o >> 7;
            int c   = ((o >> 4) & 7) ^ (row & 7);
            GLOAD16(Wt + (long)(bn + row) * K + k0 + c * 8, Wsmem + (it * 4 + wave) * 1024);
        }
        asm volatile("s_waitcnt vmcnt(0)" ::: "memory");
        __syncthreads();
        #pragma unroll
        for (int ks = 0; ks < 2; ++ks) {
            f16x8 af[4], bf[NFR];
            #pragma unroll
            for (int mi = 0; mi < 4; ++mi) {
                int row = wr * 64 + mi * 16 + l15;
                int c   = (ks * 4 + l4) ^ (row & 7);
                af[mi] = *(const f16x8*)(Asmem + row * 128 + c * 16);
            }
            #pragma unroll
            for (int ni = 0; ni < NFR; ++ni) {
                int row = wc * WN + ni * 16 + l15;
                int c   = (ks * 4 + l4) ^ (row & 7);
                bf[ni] = *(const f16x8*)(Wsmem + row * 128 + c * 16);
            }
            #pragma unroll
            for (int mi = 0; mi < 4; ++mi)
                #pragma unroll
                for (int ni = 0; ni < NFR; ++ni)
                    acc[mi][ni] = __builtin_amdgcn_mfma_f32_16x16x32_f16(
                        af[mi], bf[ni], acc[mi][ni], 0, 0, 0);
        }
        __syncthreads();
    }

    #pragma unroll
    for (int mi = 0; mi < 4; ++mi)
        #pragma unroll
        for (int r = 0; r < 4; ++r) {
            int grow = bm + wr * 64 + mi * 16 + l4 * 4 + r;
            #pragma unroll
            for (int ni = 0; ni < NFR; ++ni) {
                int gcol = bn + wc * WN + ni * 16 + l15;
                float v = acc[mi][ni][r] + bias[gcol];
                if (act) v = fmaxf(v, 0.0f);
                C[(long)grow * ldc + gcol] = v;
            }
        }
}

// ---------------- batched gi GEMM: out[l][b][768] f16, grid.z = layer -------
__global__ __launch_bounds__(256) void gi_gemm(
    const _Float16* __restrict__ A, int K,
    const _Float16* __restrict__ Wbase,
    const float* __restrict__ bbase,
    _Float16* __restrict__ outbase)
{
    constexpr int BM = 128, BN = 128, NFR = 4;
    __shared__ char smem[(BM + BN) * 128];
    char* Asmem = smem;
    char* Wsmem = smem + BM * 128;

    const _Float16* Wt = Wbase + (long)blockIdx.z * G3_ * K;
    const float* bias  = bbase + (long)blockIdx.z * G3_;
    _Float16* Cout     = outbase + (long)blockIdx.z * B_ * G3_;

    const int tid  = threadIdx.x;
    const int wave = tid >> 6;
    const int lane = tid & 63;
    const int wr   = wave >> 1;
    const int wc   = wave & 1;
    const int bm   = blockIdx.y * BM;
    const int bn   = blockIdx.x * BN;
    const int l15  = lane & 15;
    const int l4   = lane >> 4;

    f32x4 acc[4][NFR];
    #pragma unroll
    for (int a = 0; a < 4; ++a)
        #pragma unroll
        for (int b = 0; b < NFR; ++b) {
            f32x4 zz = {0.f, 0.f, 0.f, 0.f};
            acc[a][b] = zz;
        }

    for (int k0 = 0; k0 < K; k0 += 64) {
        #pragma unroll
        for (int it = 0; it < 4; ++it) {
            int o   = (it * 4 + wave) * 1024 + lane * 16;
            int row = o >> 7;
            int c   = ((o >> 4) & 7) ^ (row & 7);
            GLOAD16(A + (long)(bm + row) * K + k0 + c * 8, Asmem + (it * 4 + wave) * 1024);
        }
        #pragma unroll
        for (int it = 0; it < 4; ++it) {
            int o   = (it * 4 + wave) * 1024 + lane * 16;
            int row = o >> 7;
            int c   = ((o >> 4) & 7) ^ (row & 7);
            GLOAD16(Wt + (long)(bn + row) * K + k0 + c * 8, Wsmem + (it * 4 + wave) * 1024);
        }
        asm volatile("s_waitcnt vmcnt(0)" ::: "memory");
        __syncthreads();
        #pragma unroll
        for (int ks = 0; ks < 2; ++ks) {
            f16x8 af[4], bf[NFR];
            #pragma unroll
            for (int mi = 0; mi < 4; ++mi) {
                int row = wr * 64 + mi * 16 + l15;
                int c   = (ks * 4 + l4) ^ (row & 7);
                af[mi] = *(const f16x8*)(Asmem + row * 128 + c * 16);
            }
            #pragma unroll
            for (int ni = 0; ni < NFR; ++ni) {
                int row = wc * 64 + ni * 16 + l15;
                int c   = (ks * 4 + l4) ^ (row & 7);
                bf[ni] = *(const f16x8*)(Wsmem + row * 128 + c * 16);
            }
            #pragma unroll
            for (int mi = 0; mi < 4; ++mi)
                #pragma unroll
                for (int ni = 0; ni < NFR; ++ni)
                    acc[mi][ni] = __builtin_amdgcn_mfma_f32_16x16x32_f16(
                        af[mi], bf[ni], acc[mi][ni], 0, 0, 0);
        }
        __syncthreads();
    }

    #pragma unroll
    for (int mi = 0; mi < 4; ++mi)
        #pragma unroll
        for (int r = 0; r < 4; ++r) {
            int grow = bm + wr * 64 + mi * 16 + l4 * 4 + r;
            #pragma unroll
            for (int ni = 0; ni < NFR; ++ni) {
                int gcol = bn + wc * 64 + ni * 16 + l15;
                Cout[(long)grow * G3_ + gcol] = (_Float16)(acc[mi][ni][r] + bias[gcol]);
            }
        }
}

// ------- fused gh GEMM (3 gates x 64 h per block) + GRU combine + eps -------
// MODE 1: enc (t >= .5); MODE 2: dec (t > .5)
template<int MODE>
__global__ __launch_bounds__(256) void gru_fused(
    const _Float16* __restrict__ A,      // zh_cur [B][256]
    const _Float16* __restrict__ Whh,    // [768][256]
    const float* __restrict__ bhh,       // [768]
    const _Float16* __restrict__ gi,     // [B][768] (with bih)
    const float* __restrict__ ec,        // [768] extra col
    const float* __restrict__ tcol,      // stride L_
    const float* __restrict__ eps,       // [B][256]
    float* __restrict__ z,               // [B][256] io
    _Float16* __restrict__ zh_out)       // [B][256]
{
    constexpr int K = 256;
    __shared__ char smem[(128 + 192) * 128];
    char* Asmem = smem;
    char* Wsmem = smem + 128 * 128;

    const int tid  = threadIdx.x;
    const int wave = tid >> 6;
    const int lane = tid & 63;
    const int wr   = wave >> 1;
    const int wc   = wave & 1;
    const int bm   = blockIdx.y * 128;
    const int h0   = blockIdx.x * 64;
    const int l15  = lane & 15;
    const int l4   = lane >> 4;

    f32x4 acc[4][6];
    #pragma unroll
    for (int a = 0; a < 4; ++a)
        #pragma unroll
        for (int b = 0; b < 6; ++b) {
            f32x4 zz = {0.f, 0.f, 0.f, 0.f};
            acc[a][b] = zz;
        }

    for (int k0 = 0; k0 < K; k0 += 64) {
        #pragma unroll
        for (int it = 0; it < 4; ++it) {
            int o   = (it * 4 + wave) * 1024 + lane * 16;
            int row = o >> 7;
            int c   = ((o >> 4) & 7) ^ (row & 7);
            GLOAD16(A + (long)(bm + row) * K + k0 + c * 8, Asmem + (it * 4 + wave) * 1024);
        }
        #pragma unroll
        for (int it = 0; it < 6; ++it) {
            int o   = (it * 4 + wave) * 1024 + lane * 16;
            int rr  = o >> 7;
            int c   = ((o >> 4) & 7) ^ (rr & 7);
            int srow = (rr >> 6) * 256 + h0 + (rr & 63);
            GLOAD16(Whh + (long)srow * K + k0 + c * 8, Wsmem + (it * 4 + wave) * 1024);
        }
        asm volatile("s_waitcnt vmcnt(0)" ::: "memory");
        __syncthreads();
        #pragma unroll
        for (int ks = 0; ks < 2; ++ks) {
            f16x8 af[4], bf[6];
            #pragma unroll
            for (int mi = 0; mi < 4; ++mi) {
                int row = wr * 64 + mi * 16 + l15;
                int c   = (ks * 4 + l4) ^ (row & 7);
                af[mi] = *(const f16x8*)(Asmem + row * 128 + c * 16);
            }
            #pragma unroll
            for (int ni = 0; ni < 6; ++ni) {
                int rr = (ni >> 1) * 64 + wc * 32 + (ni & 1) * 16 + l15;
                int c  = (ks * 4 + l4) ^ (rr & 7);
                bf[ni] = *(const f16x8*)(Wsmem + rr * 128 + c * 16);
            }
            #pragma unroll
            for (int mi = 0; mi < 4; ++mi)
                #pragma unroll
                for (int ni = 0; ni < 6; ++ni)
                    acc[mi][ni] = __builtin_amdgcn_mfma_f32_16x16x32_f16(
                        af[mi], bf[ni], acc[mi][ni], 0, 0, 0);
        }
        __syncthreads();
    }

    #pragma unroll
    for (int mi = 0; mi < 4; ++mi)
        #pragma unroll
        for (int r = 0; r < 4; ++r) {
            int grow = bm + wr * 64 + mi * 16 + l4 * 4 + r;
            float tv = tcol[(long)grow * L_];
            float ext = (MODE == 1) ? (tv >= 0.5f ? 1.0f : 0.0f)
                                    : (tv >  0.5f ? 1.0f : 0.0f);
            const _Float16* gib = gi + (long)grow * G3_;
            #pragma unroll
            for (int hb = 0; hb < 2; ++hb) {
                int h = h0 + wc * 32 + hb * 16 + l15;
                float hr = acc[mi][hb][r]     + bhh[h];
                float hz = acc[mi][2 + hb][r] + bhh[256 + h];
                float hn = acc[mi][4 + hb][r] + bhh[512 + h];
                float ir = (float)gib[h]       + ext * ec[h];
                float iz = (float)gib[256 + h] + ext * ec[256 + h];
                float in_= (float)gib[512 + h] + ext * ec[512 + h];
                float rg = sigm(ir + hr);
                float zt = sigm(iz + hz);
                float n  = tanhf(in_ + rg * hn);
                long zi = (long)grow * 256 + h;
                float v = (1.0f - zt) * n + zt * z[zi] + STDF * eps[zi];
                z[zi] = v;
                zh_out[zi] = (_Float16)v;
            }
        }
}

// ------- predict head: sigm(wo . relu(A@Wd^T + bd) + bo) -> out[b*ostride] --
__global__ __launch_bounds__(256) void predict_head(
    const _Float16* __restrict__ A, int K,
    const _Float16* __restrict__ Wd,     // [256][K]
    const float* __restrict__ bd,        // [256]
    const float* __restrict__ wo,        // [256]
    const float* __restrict__ bo,
    float* __restrict__ out, int ostride)
{
    __shared__ char smem[(128 + 256) * 128];
    __shared__ float part[128][2];
    char* Asmem = smem;
    char* Wsmem = smem + 128 * 128;

    const int tid  = threadIdx.x;
    const int wave = tid >> 6;
    const int lane = tid & 63;
    const int wr   = wave >> 1;
    const int wc   = wave & 1;
    const int bm   = blockIdx.x * 128;
    const int l15  = lane & 15;
    const int l4   = lane >> 4;

    f32x4 acc[4][8];
    #pragma unroll
    for (int a = 0; a < 4; ++a)
        #pragma unroll
        for (int b = 0; b < 8; ++b) {
            f32x4 zz = {0.f, 0.f, 0.f, 0.f};
            acc[a][b] = zz;
        }

    for (int k0 = 0; k0 < K; k0 += 64) {
        #pragma unroll
        for (int it = 0; it < 4; ++it) {
            int o   = (it * 4 + wave) * 1024 + lane * 16;
            int row = o >> 7;
            int c   = ((o >> 4) & 7) ^ (row & 7);
            GLOAD16(A + (long)(bm + row) * K + k0 + c * 8, Asmem + (it * 4 + wave) * 1024);
        }
        #pragma unroll
        for (int it = 0; it < 8; ++it) {
            int o   = (it * 4 + wave) * 1024 + lane * 16;
            int row = o >> 7;
            int c   = ((o >> 4) & 7) ^ (row & 7);
            GLOAD16(Wd + (long)row * K + k0 + c * 8, Wsmem + (it * 4 + wave) * 1024);
        }
        asm volatile("s_waitcnt vmcnt(0)" ::: "memory");
        __syncthreads();
        #pragma unroll
        for (int ks = 0; ks < 2; ++ks) {
            f16x8 af[4], bf[8];
            #pragma unroll
            for (int mi = 0; mi < 4; ++mi) {
                int row = wr * 64 + mi * 16 + l15;
                int c   = (ks * 4 + l4) ^ (row & 7);
                af[mi] = *(const f16x8*)(Asmem + row * 128 + c * 16);
            }
            #pragma unroll
            for (int ni = 0; ni < 8; ++ni) {
                int row = wc * 128 + ni * 16 + l15;
                int c   = (ks * 4 + l4) ^ (row & 7);
                bf[ni] = *(const f16x8*)(Wsmem + row * 128 + c * 16);
            }
            #pragma unroll
            for (int mi = 0; mi < 4; ++mi)
                #pragma unroll
                for (int ni = 0; ni < 8; ++ni)
                    acc[mi][ni] = __builtin_amdgcn_mfma_f32_16x16x32_f16(
                        af[mi], bf[ni], acc[mi][ni], 0, 0, 0);
        }
        __syncthreads();
    }

    float bdv[8], wov[8];
    #pragma unroll
    for (int ni = 0; ni < 8; ++ni) {
        int col = wc * 128 + ni * 16 + l15;
        bdv[ni] = bd[col];
        wov[ni] = wo[col];
    }
    #pragma unroll
    for (int mi = 0; mi < 4; ++mi)
        #pragma unroll
        for (int r = 0; r < 4; ++r) {
            float s = 0.0f;
            #pragma unroll
            for (int ni = 0; ni < 8; ++ni) {
                float v = fmaxf(acc[mi][ni][r] + bdv[ni], 0.0f);
                s = fmaf(v, wov[ni], s);
            }
            #pragma unroll
            for (int off = 1; off < 16; off <<= 1) s += __shfl_xor(s, off, 16);
            if (l15 == 0) part[wr * 64 + mi * 16 + l4 * 4 + r][wc] = s;
        }
    __syncthreads();
    if (tid < 128) {
        float u = part[tid][0] + part[tid][1] + bo[0];
        out[(long)(bm + tid) * ostride] = sigm(u);
    }
}

// ---------------- f32 -> f16 strided conversion ----------------------------
__global__ __launch_bounds__(256) void conv_f16(
    const float* __restrict__ src, _Float16* __restrict__ dst,
    int Ks, int Kd, long total)
{
    long i = ((long)blockIdx.x * 256 + threadIdx.x) * 8;
    if (i >= total) return;
    long r = i / Kd, k = i - r * Kd;
    const float* s = src + r * Ks + k;
    f16x8 o;
    #pragma unroll
    for (int j = 0; j < 8; ++j) o[j] = (_Float16)s[j];
    *(f16x8*)(dst + i) = o;
}

__global__ __launch_bounds__(256) void extract_col(
    const float* __restrict__ src, float* __restrict__ dst, int Ks, int col, int R)
{
    int i = blockIdx.x * 256 + threadIdx.x;
    if (i < R) dst[i] = src[(long)i * Ks + col];
}

__global__ void stack_bias(const float* __restrict__ a, const float* __restrict__ b,
                           float* __restrict__ o)
{
    int i = threadIdx.x;
    o[i] = (i < 64) ? a[i] : b[i - 64];
}

__global__ __launch_bounds__(256) void zero2_kernel(
    float* __restrict__ z, _Float16* __restrict__ zh, int n)
{
    int i = blockIdx.x * 256 + threadIdx.x;
    if (i < n) { z[i] = 0.0f; zh[i] = (_Float16)0.0f; }
}

__global__ __launch_bounds__(256) void zero_kernel(float* __restrict__ p, int n)
{
    int i = blockIdx.x * 256 + threadIdx.x;
    if (i < n) p[i] = 0.0f;
}

// ---------------- latent elementwise (after muv GEMM) -----------------------
__global__ __launch_bounds__(256) void latent_elem(
    const float* __restrict__ muv,      // [B][128]: mu | lv_raw
    const float* __restrict__ seps,
    float* __restrict__ latent, _Float16* __restrict__ lath,
    float* __restrict__ lq, float* __restrict__ lpz)
{
    int wave = threadIdx.x >> 6, lane = threadIdx.x & 63;
    int b = blockIdx.x * 4 + wave;
    float mu = muv[(long)b * 128 + lane];
    float sp = muv[(long)b * 128 + 64 + lane];
    float lv = (sp > 0.0f) ? (sp + log1pf(expf(-sp))) : log1pf(expf(sp));
    float e  = seps[(long)b * Z_ + lane];
    float lat = mu + expf(0.5f * lv) * e;
    latent[(long)b * Z_ + lane] = lat;
    lath[(long)b * Z_ + lane] = (_Float16)lat;
    float lpz_c = -CC - 0.5f * lat * lat;
    float d = lat - mu;
    float lq_c = -CC - 0.5f * lv - d * d / (2.0f * expf(lv));
    #pragma unroll
    for (int off = 32; off; off >>= 1) {
        lpz_c += __shfl_down(lpz_c, off);
        lq_c  += __shfl_down(lq_c, off);
    }
    if (lane == 0) { lpz[b] = lpz_c; lq[b] = lq_c; }
}

// ---------------- decoder heads + BCE, 32 rows/block ------------------------
__global__ __launch_bounds__(256) void dec_pred_bce(
    const float* __restrict__ D, const float* __restrict__ Wo,
    const float* __restrict__ bo, const float* __restrict__ workers,
    float* __restrict__ acc, int l)
{
    __shared__ float ds[32][257];
    __shared__ float part[8][32];
    int tid = threadIdx.x;
    int b0 = blockIdx.x * 32;
    for (int i = 0; i < 32; ++i) {
        int idx = tid + i * 256;
        int r = idx >> 8, cc = idx & 255;
        ds[r][cc] = D[(long)(b0 + r) * H_ + cc];
    }
    __syncthreads();
    int r = tid & 31;
    int g = tid >> 5;
    const float* w0 = Wo + (long)(g * 4 + 0) * H_;
    const float* w1 = Wo + (long)(g * 4 + 1) * H_;
    const float* w2 = Wo + (long)(g * 4 + 2) * H_;
    const float* w3 = Wo + (long)(g * 4 + 3) * H_;
    float s0 = 0.f, s1 = 0.f, s2 = 0.f, s3 = 0.f;
    for (int i = 0; i < H_; ++i) {
        float d = ds[r][i];
        s0 = fmaf(d, w0[i], s0);
        s1 = fmaf(d, w1[i], s1);
        s2 = fmaf(d, w2[i], s2);
        s3 = fmaf(d, w3[i], s3);
    }
    int b = b0 + r;
    float sv[4] = {s0, s1, s2, s3};
    float tot = 0.0f;
    #pragma unroll
    for (int j = 0; j < 4; ++j) {
        int w = g * 4 + j;
        float u = sv[j] + bo[w];
        float logp   = fmaxf(logsig(u),  -100.0f);
        float log1mp = fmaxf(logsig(-u), -100.0f);
        float wk = workers[((long)w * B_ + b) * L_ + l];
        tot += -(wk * logp + (1.0f - wk) * log1mp);
    }
    part[g][r] = tot;
    __syncthreads();
    if (tid < 32) {
        float t2 = 0.0f;
        #pragma unroll
        for (int g2 = 0; g2 < 8; ++g2) t2 += part[g2][tid];
        acc[b0 + tid] += t2;
    }
}

// ---------------- log_p_x from logits ---------------------------------------
__global__ __launch_bounds__(256) void logpx_reduce(
    const float* __restrict__ u, const float* __restrict__ x,
    float* __restrict__ lpx)
{
    int wave = threadIdx.x >> 6, lane = threadIdx.x & 63;
    int b = blockIdx.x * 4 + wave;
    const float* ub = u + (long)b * X_;
    const float* xb = x + (long)b * X_;
    float s = 0.0f;
    #pragma unroll
    for (int i = 0; i < 8; ++i) {
        int k = lane + i * 64;
        s = fmaf(xb[k], logsig(ub[k]), s);
    }
    #pragma unroll
    for (int off = 32; off; off >>= 1) s += __shfl_down(s, off);
    if (lane == 0) lpx[b] = s;
}

// ---------------- KL term ---------------------------------------------------
__global__ __launch_bounds__(256) void kl_kernel(
    const float* __restrict__ tmat, const float* __restrict__ workers,
    float* __restrict__ lkl)
{
    int b = blockIdx.x * 256 + threadIdx.x;
    float wb[L_];
    #pragma unroll
    for (int l = 0; l < L_; ++l) wb[l] = 0.0f;
    for (int w = 0; w < W_; ++w) {
        const float* p = workers + ((long)w * B_ + b) * L_;
        #pragma unroll
        for (int l = 0; l < L_; ++l) wb[l] += p[l];
    }
    float s = 0.0f;
    #pragma unroll
    for (int l = 0; l < L_; ++l) {
        float wbar = wb[l] * (1.0f / 32.0f);
        float tv = tmat[(long)b * L_ + l];
        s += tv * (logf(tv + 1e-6f) - logf(wbar + 1e-6f));
    }
    lkl[b] = s;
}

// ---------------- final reduction ------------------------------------------
__global__ __launch_bounds__(1024) void final_reduce(
    const float* __restrict__ lq, const float* __restrict__ lpz,
    const float* __restrict__ bacc, const float* __restrict__ lpx,
    const float* __restrict__ lkl, float* __restrict__ out)
{
    __shared__ float red[16];
    float s = 0.0f;
    for (int b = threadIdx.x; b < B_; b += 1024)
        s += lq[b] - lpz[b] + bacc[b] - lpx[b] + lkl[b];
    #pragma unroll
    for (int off = 32; off; off >>= 1) s += __shfl_down(s, off);
    int wave = threadIdx.x >> 6, lane = threadIdx.x & 63;
    if (lane == 0) red[wave] = s;
    __syncthreads();
    if (threadIdx.x == 0) {
        float t = 0.0f;
        for (int i = 0; i < 16; ++i) t += red[i];
        out[0] = t / (float)B_;
    }
}

extern "C" void kernel_launch(void* const* d_in, const int* in_sizes, int n_in,
                              void* d_out, int out_size, void* d_ws, size_t ws_size,
                              hipStream_t stream)
{
    const float* x       = (const float*)d_in[0];
    const float* workers = (const float*)d_in[1];
    const float* Wf1     = (const float*)d_in[2];
    const float* bf1     = (const float*)d_in[3];
    const float* Wf2     = (const float*)d_in[4];
    const float* bf2     = (const float*)d_in[5];
    const float* eWih    = (const float*)d_in[6];
    const float* eWhh    = (const float*)d_in[7];
    const float* ebih    = (const float*)d_in[8];
    const float* ebhh    = (const float*)d_in[9];
    const float* eWd     = (const float*)d_in[10];
    const float* ebd     = (const float*)d_in[11];
    const float* eWo     = (const float*)d_in[12];
    const float* ebo     = (const float*)d_in[13];
    const float* Wmu     = (const float*)d_in[14];
    const float* bmu     = (const float*)d_in[15];
    const float* Wlv     = (const float*)d_in[16];
    const float* blv     = (const float*)d_in[17];
    const float* dWih    = (const float*)d_in[18];
    const float* dWhh    = (const float*)d_in[19];
    const float* dbih    = (const float*)d_in[20];
    const float* dbhh    = (const float*)d_in[21];
    const float* dWd     = (const float*)d_in[22];
    const float* dbd     = (const float*)d_in[23];
    const float* dWo     = (const float*)d_in[24];
    const float* dbo     = (const float*)d_in[25];
    const float* Wr      = (const float*)d_in[26];
    const float* br      = (const float*)d_in[27];
    const float* enc_eps = (const float*)d_in[28];
    const float* samp_eps= (const float*)d_in[29];
    const float* dec_eps = (const float*)d_in[30];

    float* t    = (float*)d_out;
    float* loss = t + (long)B_ * L_;

    char* p = (char*)d_ws;
    auto alloc = [&](size_t bytes) {
        char* r = p;
        p += (bytes + 255) & ~(size_t)255;
        return r;
    };
    _Float16* xh    = (_Float16*)alloc((size_t)B_ * X_ * 2);
    _Float16* zha   = (_Float16*)alloc((size_t)B_ * H_ * 2);
    _Float16* zhb   = (_Float16*)alloc((size_t)B_ * H_ * 2);
    _Float16* lath  = (_Float16*)alloc((size_t)B_ * Z_ * 2);
    _Float16* Wf1h  = (_Float16*)alloc((size_t)H_ * X_ * 2);
    _Float16* eWihh = (_Float16*)alloc((size_t)L_ * G3_ * X_ * 2);
    _Float16* eWhhh = (_Float16*)alloc((size_t)L_ * G3_ * H_ * 2);
    _Float16* eWdh  = (_Float16*)alloc((size_t)L_ * H_ * H_ * 2);
    _Float16* dWihh = (_Float16*)alloc((size_t)L_ * G3_ * Z_ * 2);
    _Float16* dWhhh = (_Float16*)alloc((size_t)L_ * G3_ * H_ * 2);
    _Float16* dWdh  = (_Float16*)alloc((size_t)L_ * H_ * H_ * 2);
    _Float16* Wrh   = (_Float16*)alloc((size_t)X_ * H_ * 2);
    _Float16* Wmlh  = (_Float16*)alloc((size_t)128 * H_ * 2);
    float* bml    = (float*)alloc(128 * 4);
    float* eWihc  = (float*)alloc((size_t)L_ * G3_ * 4);
    float* dWihc  = (float*)alloc((size_t)L_ * G3_ * 4);
    float* z      = (float*)alloc((size_t)B_ * H_ * 4);
    float* dbuf   = (float*)alloc((size_t)B_ * H_ * 4);
    float* latent = (float*)alloc((size_t)B_ * Z_ * 4);
    float* lq     = (float*)alloc((size_t)B_ * 4);
    float* lpz    = (float*)alloc((size_t)B_ * 4);
    float* lpx    = (float*)alloc((size_t)B_ * 4);
    float* lkl    = (float*)alloc((size_t)B_ * 4);
    float* bacc   = (float*)alloc((size_t)B_ * 4);

    // gi chunk buffer takes the rest of the workspace
    size_t used = (size_t)(p - (char*)d_ws);
    size_t per_layer = (size_t)B_ * G3_ * 2;
    size_t avail = (ws_size > used) ? (ws_size - used) : 0;
    int C = (int)(avail / per_layer);
    if (C < 1) C = 1;
    if (C > L_) C = L_;
    _Float16* gi_all = (_Float16*)alloc((size_t)C * per_layer);
    float* logits = (float*)gi_all;   // reused after decoder for recon logits

    const dim3 blk(256);
    const int nBH = B_ * H_;
    auto cgrid = [](long total) { return dim3((unsigned)((total / 8 + 255) / 256)); };

    // ---- conversions ----
    conv_f16<<<cgrid((long)B_ * X_), blk, 0, stream>>>(x, xh, X_, X_, (long)B_ * X_);
    conv_f16<<<cgrid((long)H_ * X_), blk, 0, stream>>>(Wf1, Wf1h, X_, X_, (long)H_ * X_);
    conv_f16<<<cgrid((long)L_ * G3_ * X_), blk, 0, stream>>>(eWih, eWihh, X_ + 1, X_, (long)L_ * G3_ * X_);
    conv_f16<<<cgrid((long)L_ * G3_ * H_), blk, 0, stream>>>(eWhh, eWhhh, H_, H_, (long)L_ * G3_ * H_);
    conv_f16<<<cgrid((long)L_ * H_ * H_), blk, 0, stream>>>(eWd, eWdh, H_, H_, (long)L_ * H_ * H_);
    conv_f16<<<cgrid((long)L_ * G3_ * Z_), blk, 0, stream>>>(dWih, dWihh, Z_ + 1, Z_, (long)L_ * G3_ * Z_);
    conv_f16<<<cgrid((long)L_ * G3_ * H_), blk, 0, stream>>>(dWhh, dWhhh, H_, H_, (long)L_ * G3_ * H_);
    conv_f16<<<cgrid((long)L_ * H_ * H_), blk, 0, stream>>>(dWd, dWdh, H_, H_, (long)L_ * H_ * H_);
    conv_f16<<<cgrid((long)X_ * H_), blk, 0, stream>>>(Wr, Wrh, H_, H_, (long)X_ * H_);
    conv_f16<<<cgrid((long)Z_ * H_), blk, 0, stream>>>(Wmu, Wmlh, H_, H_, (long)Z_ * H_);
    conv_f16<<<cgrid((long)Z_ * H_), blk, 0, stream>>>(Wlv, Wmlh + (long)Z_ * H_, H_, H_, (long)Z_ * H_);
    stack_bias<<<1, 128, 0, stream>>>(bmu, blv, bml);
    extract_col<<<(L_ * G3_ + 255) / 256, blk, 0, stream>>>(eWih, eWihc, X_ + 1, X_, L_ * G3_);
    extract_col<<<(L_ * G3_ + 255) / 256, blk, 0, stream>>>(dWih, dWihc, Z_ + 1, Z_, L_ * G3_);

    // ---- first cell: t[:,0] ----
    zero2_kernel<<<(nBH + 255) / 256, blk, 0, stream>>>(z, zha, nBH);
    predict_head<<<B_ / 128, blk, 0, stream>>>(xh, X_, Wf1h, bf1, Wf2, bf2, t, L_);

    // ---- encoder scan ----
    _Float16* zcur = zha;
    _Float16* znxt = zhb;
    for (int l0 = 0; l0 < L_; l0 += C) {
        int nc = (l0 + C <= L_) ? C : (L_ - l0);
        gi_gemm<<<dim3(G3_ / 128, B_ / 128, nc), blk, 0, stream>>>(
            xh, X_, eWihh + (long)l0 * G3_ * X_, ebih + (long)l0 * G3_, gi_all);
        for (int l = l0; l < l0 + nc; ++l) {
            gru_fused<1><<<dim3(4, B_ / 128), blk, 0, stream>>>(
                zcur, eWhhh + (long)l * G3_ * H_, ebhh + (long)l * G3_,
                gi_all + (long)(l - l0) * B_ * G3_, eWihc + (long)l * G3_,
                t + l, enc_eps + (long)l * nBH, z, znxt);
            _Float16* tmp = zcur; zcur = znxt; znxt = tmp;
            if (l < L_ - 1)
                predict_head<<<B_ / 128, blk, 0, stream>>>(
                    zcur, H_, eWdh + (long)l * H_ * H_, ebd + (long)l * H_,
                    eWo + (long)l * H_, ebo + l, t + (l + 1), L_);
        }
    }

    // ---- latent: muv GEMM (into dbuf) + elementwise ----
    mfma_gemm<64><<<dim3(2, B_ / 128), blk, 0, stream>>>(
        zcur, Wmlh, bml, dbuf, 128, H_, 0);
    latent_elem<<<B_ / 4, blk, 0, stream>>>(dbuf, samp_eps, latent, lath, lq, lpz);

    // ---- decoder scan ----
    zero2_kernel<<<(nBH + 255) / 256, blk, 0, stream>>>(z, zha, nBH);
    zero_kernel<<<(B_ + 255) / 256, blk, 0, stream>>>(bacc, B_);
    zcur = zha; znxt = zhb;
    for (int l0 = 0; l0 < L_; l0 += C) {
        int nc = (l0 + C <= L_) ? C : (L_ - l0);
        gi_gemm<<<dim3(G3_ / 128, B_ / 128, nc), blk, 0, stream>>>(
            lath, Z_, dWihh + (long)l0 * G3_ * Z_, dbih + (long)l0 * G3_, gi_all);
        for (int l = l0; l < l0 + nc; ++l) {
            gru_fused<2><<<dim3(4, B_ / 128), blk, 0, stream>>>(
                zcur, dWhhh + (long)l * G3_ * H_, dbhh + (long)l * G3_,
                gi_all + (long)(l - l0) * B_ * G3_, dWihc + (long)l * G3_,
                t + l, dec_eps + (long)l * nBH, z, znxt);
            _Float16* tmp = zcur; zcur = znxt; znxt = tmp;
            mfma_gemm<64><<<dim3(4, B_ / 128), blk, 0, stream>>>(
                zcur, dWdh + (long)l * H_ * H_, dbd + (long)l * H_,
                dbuf, H_, H_, 1);
            dec_pred_bce<<<B_ / 32, blk, 0, stream>>>(
                dbuf, dWo + (long)l * W_ * H_, dbo + (long)l * W_, workers, bacc, l);
        }
    }

    // ---- recon logits -> log_p_x (logits buffer aliases gi_all, now free) ----
    mfma_gemm<128><<<dim3(X_ / 128, B_ / 128), blk, 0, stream>>>(
        zcur, Wrh, br, logits, X_, H_, 0);
    logpx_reduce<<<B_ / 4, blk, 0, stream>>>(logits, x, lpx);
    // ---- KL ----
    kl_kernel<<<B_ / 256, blk, 0, stream>>>(t, workers, lkl);
    // ---- final loss ----
    final_reduce<<<1, 1024, 0, stream>>>(lq, lpz, bacc, lpx, lkl, loss);
}

// Round 4
// 1912.282 us; speedup vs baseline: 4.7383x; 1.0723x over previous
//
#include <hip/hip_runtime.h>
#include <hip/hip_bf16.h>
#include <math.h>

#define B_ 8192
#define X_ 512
#define H_ 256
#define Z_ 64
#define L_ 16
#define W_ 32
#define G3_ 768

#define STDF 1.0025031276057952f
#define CC 0.9189385332046727f

typedef _Float16 f16x8 __attribute__((ext_vector_type(8)));
typedef float f32x4 __attribute__((ext_vector_type(4)));

__device__ __forceinline__ float sigm(float x) { return 1.0f / (1.0f + expf(-x)); }
__device__ __forceinline__ float logsig(float u) {
    return (u > 0.0f) ? -log1pf(expf(-u)) : (u - log1pf(expf(u)));
}

#define GLOAD16(gsrc, ldst) \
    __builtin_amdgcn_global_load_lds((const __attribute__((address_space(1))) unsigned int*)(gsrc), \
                                     (__attribute__((address_space(3))) unsigned int*)(ldst), 16, 0, 0)

// ---------------- generic MFMA f16 GEMM (f32 out) ---------------------------
template<int BN>
__global__ __launch_bounds__(256) void mfma_gemm(
    const _Float16* __restrict__ A,
    const _Float16* __restrict__ Wt,
    const float* __restrict__ bias,
    float* __restrict__ C, int ldc,
    int K, int act)
{
    constexpr int BM = 128;
    constexpr int WN = BN / 2;
    constexpr int NFR = WN / 16;
    __shared__ char smem[(BM + BN) * 128];
    char* Asmem = smem;
    char* Wsmem = smem + BM * 128;

    const int tid  = threadIdx.x;
    const int wave = tid >> 6;
    const int lane = tid & 63;
    const int wr   = wave >> 1;
    const int wc   = wave & 1;
    const int bm   = blockIdx.y * BM;
    const int bn   = blockIdx.x * BN;
    const int l15  = lane & 15;
    const int l4   = lane >> 4;

    f32x4 acc[4][NFR];
    #pragma unroll
    for (int a = 0; a < 4; ++a)
        #pragma unroll
        for (int b = 0; b < NFR; ++b) {
            f32x4 zz = {0.f, 0.f, 0.f, 0.f};
            acc[a][b] = zz;
        }

    for (int k0 = 0; k0 < K; k0 += 64) {
        #pragma unroll
        for (int it = 0; it < 4; ++it) {
            int o   = (it * 4 + wave) * 1024 + lane * 16;
            int row = o >> 7;
            int c   = ((o >> 4) & 7) ^ (row & 7);
            GLOAD16(A + (long)(bm + row) * K + k0 + c * 8, Asmem + (it * 4 + wave) * 1024);
        }
        #pragma unroll
        for (int it = 0; it < BN / 32; ++it) {
            int o   = (it * 4 + wave) * 1024 + lane * 16;
            int row = o >> 7;
            int c   = ((o >> 4) & 7) ^ (row & 7);
            GLOAD16(Wt + (long)(bn + row) * K + k0 + c * 8, Wsmem + (it * 4 + wave) * 1024);
        }
        asm volatile("s_waitcnt vmcnt(0)" ::: "memory");
        __syncthreads();
        #pragma unroll
        for (int ks = 0; ks < 2; ++ks) {
            f16x8 af[4], bf[NFR];
            #pragma unroll
            for (int mi = 0; mi < 4; ++mi) {
                int row = wr * 64 + mi * 16 + l15;
                int c   = (ks * 4 + l4) ^ (row & 7);
                af[mi] = *(const f16x8*)(Asmem + row * 128 + c * 16);
            }
            #pragma unroll
            for (int ni = 0; ni < NFR; ++ni) {
                int row = wc * WN + ni * 16 + l15;
                int c   = (ks * 4 + l4) ^ (row & 7);
                bf[ni] = *(const f16x8*)(Wsmem + row * 128 + c * 16);
            }
            #pragma unroll
            for (int mi = 0; mi < 4; ++mi)
                #pragma unroll
                for (int ni = 0; ni < NFR; ++ni)
                    acc[mi][ni] = __builtin_amdgcn_mfma_f32_16x16x32_f16(
                        af[mi], bf[ni], acc[mi][ni], 0, 0, 0);
        }
        __syncthreads();
    }

    #pragma unroll
    for (int mi = 0; mi < 4; ++mi)
        #pragma unroll
        for (int r = 0; r < 4; ++r) {
            int grow = bm + wr * 64 + mi * 16 + l4 * 4 + r;
            #pragma unroll
            for (int ni = 0; ni < NFR; ++ni) {
                int gcol = bn + wc * WN + ni * 16 + l15;
                float v = acc[mi][ni][r] + bias[gcol];
                if (act) v = fmaxf(v, 0.0f);
                C[(long)grow * ldc + gcol] = v;
            }
        }
}

// ------- fused GRU step: (A2@Wih + bih + ext*ec) & (zh@Whh + bhh) + combine -
// MODE 1: enc (t >= .5); MODE 2: dec (t > .5). KX = A2 inner dim.
// grid: 256 blocks, XCD-bijective decode (8 bm-tiles per XCD).
template<int MODE, int KX>
__global__ __launch_bounds__(256) void gru_fused(
    const _Float16* __restrict__ A2,     // [B][KX] (x or latent)
    const _Float16* __restrict__ Wih,    // [768][KX]
    const float* __restrict__ bih,       // [768]
    const _Float16* __restrict__ Whh,    // [768][256]
    const float* __restrict__ bhh,       // [768]
    const float* __restrict__ ec,        // [768]
    const float* __restrict__ tcol,      // stride L_
    const float* __restrict__ eps,       // [B][256]
    const _Float16* __restrict__ zh_in,  // [B][256]
    float* __restrict__ z,               // [B][256] io
    _Float16* __restrict__ zh_out)       // [B][256]
{
    __shared__ char smem[(128 + 192) * 128];
    char* Asmem = smem;
    char* Wsmem = smem + 128 * 128;

    const int tid  = threadIdx.x;
    const int wave = tid >> 6;
    const int lane = tid & 63;
    const int wr   = wave >> 1;
    const int wc   = wave & 1;
    // XCD-bijective block swizzle: 256 blocks -> xcd gets contiguous bm range
    const int id   = blockIdx.x;
    const int xcd  = id & 7;
    const int wk   = id >> 3;            // 0..31
    const int bm   = (xcd * 8 + (wk >> 2)) * 128;
    const int h0   = (wk & 3) * 64;
    const int l15  = lane & 15;
    const int l4   = lane >> 4;

    f32x4 acc[4][6];   // [mi][r0,r1,z0,z1,hn0,hn1]
    f32x4 accN[4][2];  // [mi][in0,in1]
    #pragma unroll
    for (int a = 0; a < 4; ++a) {
        #pragma unroll
        for (int b = 0; b < 6; ++b) { f32x4 zz = {0.f,0.f,0.f,0.f}; acc[a][b] = zz; }
        #pragma unroll
        for (int b = 0; b < 2; ++b) { f32x4 zz = {0.f,0.f,0.f,0.f}; accN[a][b] = zz; }
    }

    // ---- pass 1: A2 @ Wih (r,z -> acc[0..3], n -> accN) ----
    for (int k0 = 0; k0 < KX; k0 += 64) {
        #pragma unroll
        for (int it = 0; it < 4; ++it) {
            int o   = (it * 4 + wave) * 1024 + lane * 16;
            int row = o >> 7;
            int c   = ((o >> 4) & 7) ^ (row & 7);
            GLOAD16(A2 + (long)(bm + row) * KX + k0 + c * 8, Asmem + (it * 4 + wave) * 1024);
        }
        #pragma unroll
        for (int it = 0; it < 6; ++it) {
            int o   = (it * 4 + wave) * 1024 + lane * 16;
            int rr  = o >> 7;
            int c   = ((o >> 4) & 7) ^ (rr & 7);
            int srow = (rr >> 6) * 256 + h0 + (rr & 63);
            GLOAD16(Wih + (long)srow * KX + k0 + c * 8, Wsmem + (it * 4 + wave) * 1024);
        }
        asm volatile("s_waitcnt vmcnt(0)" ::: "memory");
        __syncthreads();
        #pragma unroll
        for (int ks = 0; ks < 2; ++ks) {
            f16x8 af[4], bf[6];
            #pragma unroll
            for (int mi = 0; mi < 4; ++mi) {
                int row = wr * 64 + mi * 16 + l15;
                int c   = (ks * 4 + l4) ^ (row & 7);
                af[mi] = *(const f16x8*)(Asmem + row * 128 + c * 16);
            }
            #pragma unroll
            for (int ni = 0; ni < 6; ++ni) {
                int rr = (ni >> 1) * 64 + wc * 32 + (ni & 1) * 16 + l15;
                int c  = (ks * 4 + l4) ^ (rr & 7);
                bf[ni] = *(const f16x8*)(Wsmem + rr * 128 + c * 16);
            }
            #pragma unroll
            for (int mi = 0; mi < 4; ++mi) {
                #pragma unroll
                for (int ni = 0; ni < 4; ++ni)
                    acc[mi][ni] = __builtin_amdgcn_mfma_f32_16x16x32_f16(
                        af[mi], bf[ni], acc[mi][ni], 0, 0, 0);
                #pragma unroll
                for (int ni = 4; ni < 6; ++ni)
                    accN[mi][ni - 4] = __builtin_amdgcn_mfma_f32_16x16x32_f16(
                        af[mi], bf[ni], accN[mi][ni - 4], 0, 0, 0);
            }
        }
        __syncthreads();
    }

    // ---- pass 2: zh @ Whh (r,z -> acc[0..3], hn -> acc[4..5]) ----
    for (int k0 = 0; k0 < 256; k0 += 64) {
        #pragma unroll
        for (int it = 0; it < 4; ++it) {
            int o   = (it * 4 + wave) * 1024 + lane * 16;
            int row = o >> 7;
            int c   = ((o >> 4) & 7) ^ (row & 7);
            GLOAD16(zh_in + (long)(bm + row) * 256 + k0 + c * 8, Asmem + (it * 4 + wave) * 1024);
        }
        #pragma unroll
        for (int it = 0; it < 6; ++it) {
            int o   = (it * 4 + wave) * 1024 + lane * 16;
            int rr  = o >> 7;
            int c   = ((o >> 4) & 7) ^ (rr & 7);
            int srow = (rr >> 6) * 256 + h0 + (rr & 63);
            GLOAD16(Whh + (long)srow * 256 + k0 + c * 8, Wsmem + (it * 4 + wave) * 1024);
        }
        asm volatile("s_waitcnt vmcnt(0)" ::: "memory");
        __syncthreads();
        #pragma unroll
        for (int ks = 0; ks < 2; ++ks) {
            f16x8 af[4], bf[6];
            #pragma unroll
            for (int mi = 0; mi < 4; ++mi) {
                int row = wr * 64 + mi * 16 + l15;
                int c   = (ks * 4 + l4) ^ (row & 7);
                af[mi] = *(const f16x8*)(Asmem + row * 128 + c * 16);
            }
            #pragma unroll
            for (int ni = 0; ni < 6; ++ni) {
                int rr = (ni >> 1) * 64 + wc * 32 + (ni & 1) * 16 + l15;
                int c  = (ks * 4 + l4) ^ (rr & 7);
                bf[ni] = *(const f16x8*)(Wsmem + rr * 128 + c * 16);
            }
            #pragma unroll
            for (int mi = 0; mi < 4; ++mi)
                #pragma unroll
                for (int ni = 0; ni < 6; ++ni)
                    acc[mi][ni] = __builtin_amdgcn_mfma_f32_16x16x32_f16(
                        af[mi], bf[ni], acc[mi][ni], 0, 0, 0);
        }
        __syncthreads();
    }

    // ---- GRU combine epilogue ----
    #pragma unroll
    for (int mi = 0; mi < 4; ++mi)
        #pragma unroll
        for (int r = 0; r < 4; ++r) {
            int grow = bm + wr * 64 + mi * 16 + l4 * 4 + r;
            float tv = tcol[(long)grow * L_];
            float ext = (MODE == 1) ? (tv >= 0.5f ? 1.0f : 0.0f)
                                    : (tv >  0.5f ? 1.0f : 0.0f);
            #pragma unroll
            for (int hb = 0; hb < 2; ++hb) {
                int h = h0 + wc * 32 + hb * 16 + l15;
                float rpre = acc[mi][hb][r]     + bih[h]       + bhh[h]       + ext * ec[h];
                float zpre = acc[mi][2 + hb][r] + bih[256 + h] + bhh[256 + h] + ext * ec[256 + h];
                float hn   = acc[mi][4 + hb][r] + bhh[512 + h];
                float in_  = accN[mi][hb][r]    + bih[512 + h] + ext * ec[512 + h];
                float rg = sigm(rpre);
                float zt = sigm(zpre);
                float n  = tanhf(in_ + rg * hn);
                long zi = (long)grow * 256 + h;
                float v = (1.0f - zt) * n + zt * z[zi] + STDF * eps[zi];
                z[zi] = v;
                zh_out[zi] = (_Float16)v;
            }
        }
}

// ------- predict head: sigm(wo . relu(A@Wd^T + bd) + bo) -> out[b*ostride] --
__global__ __launch_bounds__(256) void predict_head(
    const _Float16* __restrict__ A, int K,
    const _Float16* __restrict__ Wd,
    const float* __restrict__ bd,
    const float* __restrict__ wo,
    const float* __restrict__ bo,
    float* __restrict__ out, int ostride)
{
    __shared__ char smem[(128 + 256) * 128];
    __shared__ float part[128][2];
    char* Asmem = smem;
    char* Wsmem = smem + 128 * 128;

    const int tid  = threadIdx.x;
    const int wave = tid >> 6;
    const int lane = tid & 63;
    const int wr   = wave >> 1;
    const int wc   = wave & 1;
    const int bm   = blockIdx.x * 128;
    const int l15  = lane & 15;
    const int l4   = lane >> 4;

    f32x4 acc[4][8];
    #pragma unroll
    for (int a = 0; a < 4; ++a)
        #pragma unroll
        for (int b = 0; b < 8; ++b) {
            f32x4 zz = {0.f, 0.f, 0.f, 0.f};
            acc[a][b] = zz;
        }

    for (int k0 = 0; k0 < K; k0 += 64) {
        #pragma unroll
        for (int it = 0; it < 4; ++it) {
            int o   = (it * 4 + wave) * 1024 + lane * 16;
            int row = o >> 7;
            int c   = ((o >> 4) & 7) ^ (row & 7);
            GLOAD16(A + (long)(bm + row) * K + k0 + c * 8, Asmem + (it * 4 + wave) * 1024);
        }
        #pragma unroll
        for (int it = 0; it < 8; ++it) {
            int o   = (it * 4 + wave) * 1024 + lane * 16;
            int row = o >> 7;
            int c   = ((o >> 4) & 7) ^ (row & 7);
            GLOAD16(Wd + (long)row * K + k0 + c * 8, Wsmem + (it * 4 + wave) * 1024);
        }
        asm volatile("s_waitcnt vmcnt(0)" ::: "memory");
        __syncthreads();
        #pragma unroll
        for (int ks = 0; ks < 2; ++ks) {
            f16x8 af[4], bf[8];
            #pragma unroll
            for (int mi = 0; mi < 4; ++mi) {
                int row = wr * 64 + mi * 16 + l15;
                int c   = (ks * 4 + l4) ^ (row & 7);
                af[mi] = *(const f16x8*)(Asmem + row * 128 + c * 16);
            }
            #pragma unroll
            for (int ni = 0; ni < 8; ++ni) {
                int row = wc * 128 + ni * 16 + l15;
                int c   = (ks * 4 + l4) ^ (row & 7);
                bf[ni] = *(const f16x8*)(Wsmem + row * 128 + c * 16);
            }
            #pragma unroll
            for (int mi = 0; mi < 4; ++mi)
                #pragma unroll
                for (int ni = 0; ni < 8; ++ni)
                    acc[mi][ni] = __builtin_amdgcn_mfma_f32_16x16x32_f16(
                        af[mi], bf[ni], acc[mi][ni], 0, 0, 0);
        }
        __syncthreads();
    }

    float bdv[8], wov[8];
    #pragma unroll
    for (int ni = 0; ni < 8; ++ni) {
        int col = wc * 128 + ni * 16 + l15;
        bdv[ni] = bd[col];
        wov[ni] = wo[col];
    }
    #pragma unroll
    for (int mi = 0; mi < 4; ++mi)
        #pragma unroll
        for (int r = 0; r < 4; ++r) {
            float s = 0.0f;
            #pragma unroll
            for (int ni = 0; ni < 8; ++ni) {
                float v = fmaxf(acc[mi][ni][r] + bdv[ni], 0.0f);
                s = fmaf(v, wov[ni], s);
            }
            #pragma unroll
            for (int off = 1; off < 16; off <<= 1) s += __shfl_xor(s, off, 16);
            if (l15 == 0) part[wr * 64 + mi * 16 + l4 * 4 + r][wc] = s;
        }
    __syncthreads();
    if (tid < 128) {
        float u = part[tid][0] + part[tid][1] + bo[0];
        out[(long)(bm + tid) * ostride] = sigm(u);
    }
}

// ------- decoder: D=relu(zh@Wd+bd); u=D@Wo^T+bo; BCE vs workers -> bacc -----
__global__ __launch_bounds__(256) void dec_head_bce(
    const _Float16* __restrict__ A,      // zh [B][256]
    const _Float16* __restrict__ Wd,     // [256][256]
    const float* __restrict__ bd,        // [256]
    const _Float16* __restrict__ Wo,     // [32][256] f16
    const float* __restrict__ bo,        // [32]
    const float* __restrict__ wt,        // [B][32] this layer
    float* __restrict__ bacc)
{
    __shared__ char smem[(128 + 256) * 128];
    __shared__ _Float16 ds[128 * 264];   // D tile, padded (+8 f16)
    __shared__ float part[128][2];
    char* Asmem = smem;
    char* Wsmem = smem + 128 * 128;

    const int tid  = threadIdx.x;
    const int wave = tid >> 6;
    const int lane = tid & 63;
    const int wr   = wave >> 1;
    const int wc   = wave & 1;
    const int bm   = blockIdx.x * 128;
    const int l15  = lane & 15;
    const int l4   = lane >> 4;

    f32x4 acc[4][8];
    #pragma unroll
    for (int a = 0; a < 4; ++a)
        #pragma unroll
        for (int b = 0; b < 8; ++b) {
            f32x4 zz = {0.f, 0.f, 0.f, 0.f};
            acc[a][b] = zz;
        }

    for (int k0 = 0; k0 < 256; k0 += 64) {
        #pragma unroll
        for (int it = 0; it < 4; ++it) {
            int o   = (it * 4 + wave) * 1024 + lane * 16;
            int row = o >> 7;
            int c   = ((o >> 4) & 7) ^ (row & 7);
            GLOAD16(A + (long)(bm + row) * 256 + k0 + c * 8, Asmem + (it * 4 + wave) * 1024);
        }
        #pragma unroll
        for (int it = 0; it < 8; ++it) {
            int o   = (it * 4 + wave) * 1024 + lane * 16;
            int row = o >> 7;
            int c   = ((o >> 4) & 7) ^ (row & 7);
            GLOAD16(Wd + (long)row * 256 + k0 + c * 8, Wsmem + (it * 4 + wave) * 1024);
        }
        asm volatile("s_waitcnt vmcnt(0)" ::: "memory");
        __syncthreads();
        #pragma unroll
        for (int ks = 0; ks < 2; ++ks) {
            f16x8 af[4], bf[8];
            #pragma unroll
            for (int mi = 0; mi < 4; ++mi) {
                int row = wr * 64 + mi * 16 + l15;
                int c   = (ks * 4 + l4) ^ (row & 7);
                af[mi] = *(const f16x8*)(Asmem + row * 128 + c * 16);
            }
            #pragma unroll
            for (int ni = 0; ni < 8; ++ni) {
                int row = wc * 128 + ni * 16 + l15;
                int c   = (ks * 4 + l4) ^ (row & 7);
                bf[ni] = *(const f16x8*)(Wsmem + row * 128 + c * 16);
            }
            #pragma unroll
            for (int mi = 0; mi < 4; ++mi)
                #pragma unroll
                for (int ni = 0; ni < 8; ++ni)
                    acc[mi][ni] = __builtin_amdgcn_mfma_f32_16x16x32_f16(
                        af[mi], bf[ni], acc[mi][ni], 0, 0, 0);
        }
        __syncthreads();
    }

    // D -> LDS (relu + f16)
    #pragma unroll
    for (int mi = 0; mi < 4; ++mi)
        #pragma unroll
        for (int r = 0; r < 4; ++r) {
            int row = wr * 64 + mi * 16 + l4 * 4 + r;
            #pragma unroll
            for (int ni = 0; ni < 8; ++ni) {
                int col = wc * 128 + ni * 16 + l15;
                ds[row * 264 + col] = (_Float16)fmaxf(acc[mi][ni][r] + bd[col], 0.0f);
            }
        }
    __syncthreads();

    // stage 2: u = D @ Wo^T  (N=32: wc picks 16-col half)
    f16x8 bf2[8];
    #pragma unroll
    for (int ks = 0; ks < 8; ++ks) {
        int wcol = wc * 16 + l15;
        bf2[ks] = *(const f16x8*)(Wo + (long)wcol * 256 + ks * 32 + l4 * 8);
    }
    f32x4 acc2[4];
    #pragma unroll
    for (int mi = 0; mi < 4; ++mi) { f32x4 zz = {0.f,0.f,0.f,0.f}; acc2[mi] = zz; }
    #pragma unroll
    for (int ks = 0; ks < 8; ++ks) {
        #pragma unroll
        for (int mi = 0; mi < 4; ++mi) {
            f16x8 af = *(const f16x8*)(ds + (wr * 64 + mi * 16 + l15) * 264 + ks * 32 + l4 * 8);
            acc2[mi] = __builtin_amdgcn_mfma_f32_16x16x32_f16(af, bf2[ks], acc2[mi], 0, 0, 0);
        }
    }

    // BCE epilogue
    #pragma unroll
    for (int mi = 0; mi < 4; ++mi)
        #pragma unroll
        for (int r = 0; r < 4; ++r) {
            int row = wr * 64 + mi * 16 + l4 * 4 + r;
            int w = wc * 16 + l15;
            float u = acc2[mi][r] + bo[w];
            float logp   = fmaxf(logsig(u),  -100.0f);
            float log1mp = fmaxf(logsig(-u), -100.0f);
            float wk = wt[(long)(bm + row) * W_ + w];
            float s = -(wk * logp + (1.0f - wk) * log1mp);
            #pragma unroll
            for (int off = 1; off < 16; off <<= 1) s += __shfl_xor(s, off, 16);
            if (l15 == 0) part[row][wc] = s;
        }
    __syncthreads();
    if (tid < 128) bacc[bm + tid] += part[tid][0] + part[tid][1];
}

// ---------------- workers transpose: [W][B][L] -> [L][B][W] -----------------
__global__ __launch_bounds__(256) void wtrans(
    const float* __restrict__ workers, float* __restrict__ wt)
{
    long idx = (long)blockIdx.x * 256 + threadIdx.x;   // W_*B_ threads
    int w = idx & 31;
    long b = idx >> 5;
    const float* src = workers + (w * (long)B_ + b) * L_;
    #pragma unroll
    for (int l = 0; l < L_; ++l)
        wt[((long)l * B_ + b) * W_ + w] = src[l];
}

// ---------------- f32 -> f16 strided conversion ----------------------------
__global__ __launch_bounds__(256) void conv_f16(
    const float* __restrict__ src, _Float16* __restrict__ dst,
    int Ks, int Kd, long total)
{
    long i = ((long)blockIdx.x * 256 + threadIdx.x) * 8;
    if (i >= total) return;
    long r = i / Kd, k = i - r * Kd;
    const float* s = src + r * Ks + k;
    f16x8 o;
    #pragma unroll
    for (int j = 0; j < 8; ++j) o[j] = (_Float16)s[j];
    *(f16x8*)(dst + i) = o;
}

__global__ __launch_bounds__(256) void extract_col(
    const float* __restrict__ src, float* __restrict__ dst, int Ks, int col, int R)
{
    int i = blockIdx.x * 256 + threadIdx.x;
    if (i < R) dst[i] = src[(long)i * Ks + col];
}

__global__ void stack_bias(const float* __restrict__ a, const float* __restrict__ b,
                           float* __restrict__ o)
{
    int i = threadIdx.x;
    o[i] = (i < 64) ? a[i] : b[i - 64];
}

__global__ __launch_bounds__(256) void zero2_kernel(
    float* __restrict__ z, _Float16* __restrict__ zh, int n)
{
    int i = blockIdx.x * 256 + threadIdx.x;
    if (i < n) { z[i] = 0.0f; zh[i] = (_Float16)0.0f; }
}

__global__ __launch_bounds__(256) void zero_kernel(float* __restrict__ p, int n)
{
    int i = blockIdx.x * 256 + threadIdx.x;
    if (i < n) p[i] = 0.0f;
}

// ---------------- latent elementwise (after muv GEMM) -----------------------
__global__ __launch_bounds__(256) void latent_elem(
    const float* __restrict__ muv,      // [B][128]: mu | lv_raw
    const float* __restrict__ seps,
    float* __restrict__ latent, _Float16* __restrict__ lath,
    float* __restrict__ lq, float* __restrict__ lpz)
{
    int wave = threadIdx.x >> 6, lane = threadIdx.x & 63;
    int b = blockIdx.x * 4 + wave;
    float mu = muv[(long)b * 128 + lane];
    float sp = muv[(long)b * 128 + 64 + lane];
    float lv = (sp > 0.0f) ? (sp + log1pf(expf(-sp))) : log1pf(expf(sp));
    float e  = seps[(long)b * Z_ + lane];
    float lat = mu + expf(0.5f * lv) * e;
    latent[(long)b * Z_ + lane] = lat;
    lath[(long)b * Z_ + lane] = (_Float16)lat;
    float lpz_c = -CC - 0.5f * lat * lat;
    float d = lat - mu;
    float lq_c = -CC - 0.5f * lv - d * d / (2.0f * expf(lv));
    #pragma unroll
    for (int off = 32; off; off >>= 1) {
        lpz_c += __shfl_down(lpz_c, off);
        lq_c  += __shfl_down(lq_c, off);
    }
    if (lane == 0) { lpz[b] = lpz_c; lq[b] = lq_c; }
}

// ---------------- log_p_x from logits ---------------------------------------
__global__ __launch_bounds__(256) void logpx_reduce(
    const float* __restrict__ u, const float* __restrict__ x,
    float* __restrict__ lpx)
{
    int wave = threadIdx.x >> 6, lane = threadIdx.x & 63;
    int b = blockIdx.x * 4 + wave;
    const float* ub = u + (long)b * X_;
    const float* xb = x + (long)b * X_;
    float s = 0.0f;
    #pragma unroll
    for (int i = 0; i < 8; ++i) {
        int k = lane + i * 64;
        s = fmaf(xb[k], logsig(ub[k]), s);
    }
    #pragma unroll
    for (int off = 32; off; off >>= 1) s += __shfl_down(s, off);
    if (lane == 0) lpx[b] = s;
}

// ---------------- KL term ---------------------------------------------------
__global__ __launch_bounds__(256) void kl_kernel(
    const float* __restrict__ tmat, const float* __restrict__ workers,
    float* __restrict__ lkl)
{
    int b = blockIdx.x * 256 + threadIdx.x;
    float wb[L_];
    #pragma unroll
    for (int l = 0; l < L_; ++l) wb[l] = 0.0f;
    for (int w = 0; w < W_; ++w) {
        const float* p = workers + ((long)w * B_ + b) * L_;
        #pragma unroll
        for (int l = 0; l < L_; ++l) wb[l] += p[l];
    }
    float s = 0.0f;
    #pragma unroll
    for (int l = 0; l < L_; ++l) {
        float wbar = wb[l] * (1.0f / 32.0f);
        float tv = tmat[(long)b * L_ + l];
        s += tv * (logf(tv + 1e-6f) - logf(wbar + 1e-6f));
    }
    lkl[b] = s;
}

// ---------------- final reduction ------------------------------------------
__global__ __launch_bounds__(1024) void final_reduce(
    const float* __restrict__ lq, const float* __restrict__ lpz,
    const float* __restrict__ bacc, const float* __restrict__ lpx,
    const float* __restrict__ lkl, float* __restrict__ out)
{
    __shared__ float red[16];
    float s = 0.0f;
    for (int b = threadIdx.x; b < B_; b += 1024)
        s += lq[b] - lpz[b] + bacc[b] - lpx[b] + lkl[b];
    #pragma unroll
    for (int off = 32; off; off >>= 1) s += __shfl_down(s, off);
    int wave = threadIdx.x >> 6, lane = threadIdx.x & 63;
    if (lane == 0) red[wave] = s;
    __syncthreads();
    if (threadIdx.x == 0) {
        float t = 0.0f;
        for (int i = 0; i < 16; ++i) t += red[i];
        out[0] = t / (float)B_;
    }
}

extern "C" void kernel_launch(void* const* d_in, const int* in_sizes, int n_in,
                              void* d_out, int out_size, void* d_ws, size_t ws_size,
                              hipStream_t stream)
{
    const float* x       = (const float*)d_in[0];
    const float* workers = (const float*)d_in[1];
    const float* Wf1     = (const float*)d_in[2];
    const float* bf1     = (const float*)d_in[3];
    const float* Wf2     = (const float*)d_in[4];
    const float* bf2     = (const float*)d_in[5];
    const float* eWih    = (const float*)d_in[6];
    const float* eWhh    = (const float*)d_in[7];
    const float* ebih    = (const float*)d_in[8];
    const float* ebhh    = (const float*)d_in[9];
    const float* eWd     = (const float*)d_in[10];
    const float* ebd     = (const float*)d_in[11];
    const float* eWo     = (const float*)d_in[12];
    const float* ebo     = (const float*)d_in[13];
    const float* Wmu     = (const float*)d_in[14];
    const float* bmu     = (const float*)d_in[15];
    const float* Wlv     = (const float*)d_in[16];
    const float* blv     = (const float*)d_in[17];
    const float* dWih    = (const float*)d_in[18];
    const float* dWhh    = (const float*)d_in[19];
    const float* dbih    = (const float*)d_in[20];
    const float* dbhh    = (const float*)d_in[21];
    const float* dWd     = (const float*)d_in[22];
    const float* dbd     = (const float*)d_in[23];
    const float* dWo     = (const float*)d_in[24];
    const float* dbo     = (const float*)d_in[25];
    const float* Wr      = (const float*)d_in[26];
    const float* br      = (const float*)d_in[27];
    const float* enc_eps = (const float*)d_in[28];
    const float* samp_eps= (const float*)d_in[29];
    const float* dec_eps = (const float*)d_in[30];

    float* t    = (float*)d_out;
    float* loss = t + (long)B_ * L_;

    char* p = (char*)d_ws;
    auto alloc = [&](size_t bytes) {
        char* r = p;
        p += (bytes + 255) & ~(size_t)255;
        return r;
    };
    _Float16* xh    = (_Float16*)alloc((size_t)B_ * X_ * 2);
    _Float16* zha   = (_Float16*)alloc((size_t)B_ * H_ * 2);
    _Float16* zhb   = (_Float16*)alloc((size_t)B_ * H_ * 2);
    _Float16* lath  = (_Float16*)alloc((size_t)B_ * Z_ * 2);
    _Float16* Wf1h  = (_Float16*)alloc((size_t)H_ * X_ * 2);
    _Float16* eWihh = (_Float16*)alloc((size_t)L_ * G3_ * X_ * 2);
    _Float16* eWhhh = (_Float16*)alloc((size_t)L_ * G3_ * H_ * 2);
    _Float16* eWdh  = (_Float16*)alloc((size_t)L_ * H_ * H_ * 2);
    _Float16* dWihh = (_Float16*)alloc((size_t)L_ * G3_ * Z_ * 2);
    _Float16* dWhhh = (_Float16*)alloc((size_t)L_ * G3_ * H_ * 2);
    _Float16* dWdh  = (_Float16*)alloc((size_t)L_ * H_ * H_ * 2);
    _Float16* dWoh  = (_Float16*)alloc((size_t)L_ * W_ * H_ * 2);
    _Float16* Wrh   = (_Float16*)alloc((size_t)X_ * H_ * 2);
    _Float16* Wmlh  = (_Float16*)alloc((size_t)128 * H_ * 2);
    float* bml    = (float*)alloc(128 * 4);
    float* eWihc  = (float*)alloc((size_t)L_ * G3_ * 4);
    float* dWihc  = (float*)alloc((size_t)L_ * G3_ * 4);
    float* z      = (float*)alloc((size_t)B_ * H_ * 4);
    float* dbuf   = (float*)alloc((size_t)B_ * H_ * 4);
    float* latent = (float*)alloc((size_t)B_ * Z_ * 4);
    float* wt     = (float*)alloc((size_t)L_ * B_ * W_ * 4);
    float* logits = (float*)alloc((size_t)B_ * X_ * 4);
    float* lq     = (float*)alloc((size_t)B_ * 4);
    float* lpz    = (float*)alloc((size_t)B_ * 4);
    float* lpx    = (float*)alloc((size_t)B_ * 4);
    float* lkl    = (float*)alloc((size_t)B_ * 4);
    float* bacc   = (float*)alloc((size_t)B_ * 4);

    const dim3 blk(256);
    const int nBH = B_ * H_;
    auto cgrid = [](long total) { return dim3((unsigned)((total / 8 + 255) / 256)); };

    // ---- conversions ----
    conv_f16<<<cgrid((long)B_ * X_), blk, 0, stream>>>(x, xh, X_, X_, (long)B_ * X_);
    conv_f16<<<cgrid((long)H_ * X_), blk, 0, stream>>>(Wf1, Wf1h, X_, X_, (long)H_ * X_);
    conv_f16<<<cgrid((long)L_ * G3_ * X_), blk, 0, stream>>>(eWih, eWihh, X_ + 1, X_, (long)L_ * G3_ * X_);
    conv_f16<<<cgrid((long)L_ * G3_ * H_), blk, 0, stream>>>(eWhh, eWhhh, H_, H_, (long)L_ * G3_ * H_);
    conv_f16<<<cgrid((long)L_ * H_ * H_), blk, 0, stream>>>(eWd, eWdh, H_, H_, (long)L_ * H_ * H_);
    conv_f16<<<cgrid((long)L_ * G3_ * Z_), blk, 0, stream>>>(dWih, dWihh, Z_ + 1, Z_, (long)L_ * G3_ * Z_);
    conv_f16<<<cgrid((long)L_ * G3_ * H_), blk, 0, stream>>>(dWhh, dWhhh, H_, H_, (long)L_ * G3_ * H_);
    conv_f16<<<cgrid((long)L_ * H_ * H_), blk, 0, stream>>>(dWd, dWdh, H_, H_, (long)L_ * H_ * H_);
    conv_f16<<<cgrid((long)L_ * W_ * H_), blk, 0, stream>>>(dWo, dWoh, H_, H_, (long)L_ * W_ * H_);
    conv_f16<<<cgrid((long)X_ * H_), blk, 0, stream>>>(Wr, Wrh, H_, H_, (long)X_ * H_);
    conv_f16<<<cgrid((long)Z_ * H_), blk, 0, stream>>>(Wmu, Wmlh, H_, H_, (long)Z_ * H_);
    conv_f16<<<cgrid((long)Z_ * H_), blk, 0, stream>>>(Wlv, Wmlh + (long)Z_ * H_, H_, H_, (long)Z_ * H_);
    stack_bias<<<1, 128, 0, stream>>>(bmu, blv, bml);
    extract_col<<<(L_ * G3_ + 255) / 256, blk, 0, stream>>>(eWih, eWihc, X_ + 1, X_, L_ * G3_);
    extract_col<<<(L_ * G3_ + 255) / 256, blk, 0, stream>>>(dWih, dWihc, Z_ + 1, Z_, L_ * G3_);
    wtrans<<<(W_ * B_) / 256, blk, 0, stream>>>(workers, wt);

    // ---- first cell: t[:,0] ----
    zero2_kernel<<<(nBH + 255) / 256, blk, 0, stream>>>(z, zha, nBH);
    predict_head<<<B_ / 128, blk, 0, stream>>>(xh, X_, Wf1h, bf1, Wf2, bf2, t, L_);

    // ---- encoder scan ----
    _Float16* zcur = zha;
    _Float16* znxt = zhb;
    for (int l = 0; l < L_; ++l) {
        gru_fused<1, X_><<<256, blk, 0, stream>>>(
            xh, eWihh + (long)l * G3_ * X_, ebih + (long)l * G3_,
            eWhhh + (long)l * G3_ * H_, ebhh + (long)l * G3_,
            eWihc + (long)l * G3_, t + l, enc_eps + (long)l * nBH,
            zcur, z, znxt);
        _Float16* tmp = zcur; zcur = znxt; znxt = tmp;
        if (l < L_ - 1)
            predict_head<<<B_ / 128, blk, 0, stream>>>(
                zcur, H_, eWdh + (long)l * H_ * H_, ebd + (long)l * H_,
                eWo + (long)l * H_, ebo + l, t + (l + 1), L_);
    }

    // ---- latent: muv GEMM + elementwise ----
    mfma_gemm<64><<<dim3(2, B_ / 128), blk, 0, stream>>>(
        zcur, Wmlh, bml, dbuf, 128, H_, 0);
    latent_elem<<<B_ / 4, blk, 0, stream>>>(dbuf, samp_eps, latent, lath, lq, lpz);

    // ---- decoder scan ----
    zero2_kernel<<<(nBH + 255) / 256, blk, 0, stream>>>(z, zha, nBH);
    zero_kernel<<<(B_ + 255) / 256, blk, 0, stream>>>(bacc, B_);
    zcur = zha; znxt = zhb;
    for (int l = 0; l < L_; ++l) {
        gru_fused<2, Z_><<<256, blk, 0, stream>>>(
            lath, dWihh + (long)l * G3_ * Z_, dbih + (long)l * G3_,
            dWhhh + (long)l * G3_ * H_, dbhh + (long)l * G3_,
            dWihc + (long)l * G3_, t + l, dec_eps + (long)l * nBH,
            zcur, z, znxt);
        _Float16* tmp = zcur; zcur = znxt; znxt = tmp;
        dec_head_bce<<<B_ / 128, blk, 0, stream>>>(
            zcur, dWdh + (long)l * H_ * H_, dbd + (long)l * H_,
            dWoh + (long)l * W_ * H_, dbo + (long)l * W_,
            wt + (long)l * B_ * W_, bacc);
    }

    // ---- recon logits -> log_p_x ----
    mfma_gemm<128><<<dim3(X_ / 128, B_ / 128), blk, 0, stream>>>(
        zcur, Wrh, br, logits, X_, H_, 0);
    logpx_reduce<<<B_ / 4, blk, 0, stream>>>(logits, x, lpx);
    // ---- KL ----
    kl_kernel<<<B_ / 256, blk, 0, stream>>>(t, workers, lkl);
    // ---- final loss ----
    final_reduce<<<1, 1024, 0, stream>>>(lq, lpz, bacc, lpx, lkl, loss);
}

// Round 5
// 1171.259 us; speedup vs baseline: 7.7361x; 1.6327x over previous
//
#include <hip/hip_runtime.h>
#include <hip/hip_bf16.h>
#include <math.h>

#define B_ 8192
#define X_ 512
#define H_ 256
#define Z_ 64
#define L_ 16
#define W_ 32
#define G3_ 768

#define STDF 1.0025031276057952f
#define CC 0.9189385332046727f

typedef _Float16 f16x8 __attribute__((ext_vector_type(8)));
typedef float f32x4 __attribute__((ext_vector_type(4)));

__device__ __forceinline__ float sigm(float x) { return 1.0f / (1.0f + expf(-x)); }
__device__ __forceinline__ float logsig(float u) {
    return (u > 0.0f) ? -log1pf(expf(-u)) : (u - log1pf(expf(u)));
}

#define GLOAD16(gsrc, ldst) \
    __builtin_amdgcn_global_load_lds((const __attribute__((address_space(1))) unsigned int*)(gsrc), \
                                     (__attribute__((address_space(3))) unsigned int*)(ldst), 16, 0, 0)

// ---------------- generic MFMA f16 GEMM (f32 out), BM=128 -------------------
template<int BN>
__global__ __launch_bounds__(256) void mfma_gemm(
    const _Float16* __restrict__ A,
    const _Float16* __restrict__ Wt,
    const float* __restrict__ bias,
    float* __restrict__ C, int ldc,
    int K, int act)
{
    constexpr int BM = 128;
    constexpr int WN = BN / 2;
    constexpr int NFR = WN / 16;
    __shared__ char smem[(BM + BN) * 128];
    char* Asmem = smem;
    char* Wsmem = smem + BM * 128;

    const int tid  = threadIdx.x;
    const int wave = tid >> 6;
    const int lane = tid & 63;
    const int wr   = wave >> 1;
    const int wc   = wave & 1;
    const int bm   = blockIdx.y * BM;
    const int bn   = blockIdx.x * BN;
    const int l15  = lane & 15;
    const int l4   = lane >> 4;

    f32x4 acc[4][NFR];
    #pragma unroll
    for (int a = 0; a < 4; ++a)
        #pragma unroll
        for (int b = 0; b < NFR; ++b) {
            f32x4 zz = {0.f, 0.f, 0.f, 0.f};
            acc[a][b] = zz;
        }

    for (int k0 = 0; k0 < K; k0 += 64) {
        #pragma unroll
        for (int it = 0; it < 4; ++it) {
            int o   = (it * 4 + wave) * 1024 + lane * 16;
            int row = o >> 7;
            int c   = ((o >> 4) & 7) ^ (row & 7);
            GLOAD16(A + (long)(bm + row) * K + k0 + c * 8, Asmem + (it * 4 + wave) * 1024);
        }
        #pragma unroll
        for (int it = 0; it < BN / 32; ++it) {
            int o   = (it * 4 + wave) * 1024 + lane * 16;
            int row = o >> 7;
            int c   = ((o >> 4) & 7) ^ (row & 7);
            GLOAD16(Wt + (long)(bn + row) * K + k0 + c * 8, Wsmem + (it * 4 + wave) * 1024);
        }
        asm volatile("s_waitcnt vmcnt(0)" ::: "memory");
        __syncthreads();
        #pragma unroll
        for (int ks = 0; ks < 2; ++ks) {
            f16x8 af[4], bf[NFR];
            #pragma unroll
            for (int mi = 0; mi < 4; ++mi) {
                int row = wr * 64 + mi * 16 + l15;
                int c   = (ks * 4 + l4) ^ (row & 7);
                af[mi] = *(const f16x8*)(Asmem + row * 128 + c * 16);
            }
            #pragma unroll
            for (int ni = 0; ni < NFR; ++ni) {
                int row = wc * WN + ni * 16 + l15;
                int c   = (ks * 4 + l4) ^ (row & 7);
                bf[ni] = *(const f16x8*)(Wsmem + row * 128 + c * 16);
            }
            #pragma unroll
            for (int mi = 0; mi < 4; ++mi)
                #pragma unroll
                for (int ni = 0; ni < NFR; ++ni)
                    acc[mi][ni] = __builtin_amdgcn_mfma_f32_16x16x32_f16(
                        af[mi], bf[ni], acc[mi][ni], 0, 0, 0);
        }
        __syncthreads();
    }

    #pragma unroll
    for (int mi = 0; mi < 4; ++mi)
        #pragma unroll
        for (int r = 0; r < 4; ++r) {
            int grow = bm + wr * 64 + mi * 16 + l4 * 4 + r;
            #pragma unroll
            for (int ni = 0; ni < NFR; ++ni) {
                int gcol = bn + wc * WN + ni * 16 + l15;
                float v = acc[mi][ni][r] + bias[gcol];
                if (act) v = fmaxf(v, 0.0f);
                C[(long)grow * ldc + gcol] = v;
            }
        }
}

// ------- fused GRU step, BM=64, grid 512 (2 blocks/CU) ----------------------
// (A2@Wih + bih + ext*ec) & (zh@Whh + bhh) -> combine + eps
// MODE 1: enc (t >= .5); MODE 2: dec (t > .5). KX = A2 inner dim.
template<int MODE, int KX>
__global__ __launch_bounds__(256) void gru_fused(
    const _Float16* __restrict__ A2,     // [B][KX] (x or latent)
    const _Float16* __restrict__ Wih,    // [768][KX]
    const float* __restrict__ bih,       // [768]
    const _Float16* __restrict__ Whh,    // [768][256]
    const float* __restrict__ bhh,       // [768]
    const float* __restrict__ ec,        // [768]
    const float* __restrict__ tcol,      // stride L_
    const float* __restrict__ eps,       // [B][256]
    const _Float16* __restrict__ zh_in,  // [B][256]
    float* __restrict__ z,               // [B][256] io
    _Float16* __restrict__ zh_out)       // [B][256]
{
    __shared__ char smem[(64 + 192) * 128];
    char* Asmem = smem;
    char* Wsmem = smem + 64 * 128;

    const int tid  = threadIdx.x;
    const int wave = tid >> 6;
    const int lane = tid & 63;
    const int wr   = wave >> 1;          // 32-row half
    const int wc   = wave & 1;           // 32-col half per gate
    // XCD-bijective: 512 blocks -> each XCD gets contiguous 16 bm-tiles x 4 h0
    const int id   = blockIdx.x;
    const int xcd  = id & 7;
    const int wk   = id >> 3;            // 0..63
    const int bm   = (xcd * 16 + (wk >> 2)) * 64;
    const int h0   = (wk & 3) * 64;
    const int l15  = lane & 15;
    const int l4   = lane >> 4;

    f32x4 acc[2][6];   // [mi][r0,r1,z0,z1,hn0,hn1]
    f32x4 accN[2][2];  // [mi][in0,in1]
    #pragma unroll
    for (int a = 0; a < 2; ++a) {
        #pragma unroll
        for (int b = 0; b < 6; ++b) { f32x4 zz = {0.f,0.f,0.f,0.f}; acc[a][b] = zz; }
        #pragma unroll
        for (int b = 0; b < 2; ++b) { f32x4 zz = {0.f,0.f,0.f,0.f}; accN[a][b] = zz; }
    }

    // ---- pass 1: A2 @ Wih (r,z -> acc[0..3], n -> accN) ----
    for (int k0 = 0; k0 < KX; k0 += 64) {
        #pragma unroll
        for (int it = 0; it < 2; ++it) {
            int q   = it * 4 + wave;
            int o   = q * 1024 + lane * 16;
            int row = o >> 7;
            int c   = ((o >> 4) & 7) ^ (row & 7);
            GLOAD16(A2 + (long)(bm + row) * KX + k0 + c * 8, Asmem + q * 1024);
        }
        #pragma unroll
        for (int it = 0; it < 6; ++it) {
            int q   = it * 4 + wave;
            int o   = q * 1024 + lane * 16;
            int rr  = o >> 7;
            int c   = ((o >> 4) & 7) ^ (rr & 7);
            int srow = (rr >> 6) * 256 + h0 + (rr & 63);
            GLOAD16(Wih + (long)srow * KX + k0 + c * 8, Wsmem + q * 1024);
        }
        asm volatile("s_waitcnt vmcnt(0)" ::: "memory");
        __syncthreads();
        #pragma unroll
        for (int ks = 0; ks < 2; ++ks) {
            f16x8 af[2], bf[6];
            #pragma unroll
            for (int mi = 0; mi < 2; ++mi) {
                int row = wr * 32 + mi * 16 + l15;
                int c   = (ks * 4 + l4) ^ (row & 7);
                af[mi] = *(const f16x8*)(Asmem + row * 128 + c * 16);
            }
            #pragma unroll
            for (int ni = 0; ni < 6; ++ni) {
                int rr = (ni >> 1) * 64 + wc * 32 + (ni & 1) * 16 + l15;
                int c  = (ks * 4 + l4) ^ (rr & 7);
                bf[ni] = *(const f16x8*)(Wsmem + rr * 128 + c * 16);
            }
            #pragma unroll
            for (int mi = 0; mi < 2; ++mi) {
                #pragma unroll
                for (int ni = 0; ni < 4; ++ni)
                    acc[mi][ni] = __builtin_amdgcn_mfma_f32_16x16x32_f16(
                        af[mi], bf[ni], acc[mi][ni], 0, 0, 0);
                #pragma unroll
                for (int ni = 4; ni < 6; ++ni)
                    accN[mi][ni - 4] = __builtin_amdgcn_mfma_f32_16x16x32_f16(
                        af[mi], bf[ni], accN[mi][ni - 4], 0, 0, 0);
            }
        }
        __syncthreads();
    }

    // ---- pass 2: zh @ Whh (r,z -> acc[0..3], hn -> acc[4..5]) ----
    for (int k0 = 0; k0 < 256; k0 += 64) {
        #pragma unroll
        for (int it = 0; it < 2; ++it) {
            int q   = it * 4 + wave;
            int o   = q * 1024 + lane * 16;
            int row = o >> 7;
            int c   = ((o >> 4) & 7) ^ (row & 7);
            GLOAD16(zh_in + (long)(bm + row) * 256 + k0 + c * 8, Asmem + q * 1024);
        }
        #pragma unroll
        for (int it = 0; it < 6; ++it) {
            int q   = it * 4 + wave;
            int o   = q * 1024 + lane * 16;
            int rr  = o >> 7;
            int c   = ((o >> 4) & 7) ^ (rr & 7);
            int srow = (rr >> 6) * 256 + h0 + (rr & 63);
            GLOAD16(Whh + (long)srow * 256 + k0 + c * 8, Wsmem + q * 1024);
        }
        asm volatile("s_waitcnt vmcnt(0)" ::: "memory");
        __syncthreads();
        #pragma unroll
        for (int ks = 0; ks < 2; ++ks) {
            f16x8 af[2], bf[6];
            #pragma unroll
            for (int mi = 0; mi < 2; ++mi) {
                int row = wr * 32 + mi * 16 + l15;
                int c   = (ks * 4 + l4) ^ (row & 7);
                af[mi] = *(const f16x8*)(Asmem + row * 128 + c * 16);
            }
            #pragma unroll
            for (int ni = 0; ni < 6; ++ni) {
                int rr = (ni >> 1) * 64 + wc * 32 + (ni & 1) * 16 + l15;
                int c  = (ks * 4 + l4) ^ (rr & 7);
                bf[ni] = *(const f16x8*)(Wsmem + rr * 128 + c * 16);
            }
            #pragma unroll
            for (int mi = 0; mi < 2; ++mi)
                #pragma unroll
                for (int ni = 0; ni < 6; ++ni)
                    acc[mi][ni] = __builtin_amdgcn_mfma_f32_16x16x32_f16(
                        af[mi], bf[ni], acc[mi][ni], 0, 0, 0);
        }
        __syncthreads();
    }

    // ---- GRU combine epilogue ----
    #pragma unroll
    for (int mi = 0; mi < 2; ++mi)
        #pragma unroll
        for (int r = 0; r < 4; ++r) {
            int grow = bm + wr * 32 + mi * 16 + l4 * 4 + r;
            float tv = tcol[(long)grow * L_];
            float ext = (MODE == 1) ? (tv >= 0.5f ? 1.0f : 0.0f)
                                    : (tv >  0.5f ? 1.0f : 0.0f);
            #pragma unroll
            for (int hb = 0; hb < 2; ++hb) {
                int h = h0 + wc * 32 + hb * 16 + l15;
                float rpre = acc[mi][hb][r]     + bih[h]       + bhh[h]       + ext * ec[h];
                float zpre = acc[mi][2 + hb][r] + bih[256 + h] + bhh[256 + h] + ext * ec[256 + h];
                float hn   = acc[mi][4 + hb][r] + bhh[512 + h];
                float in_  = accN[mi][hb][r]    + bih[512 + h] + ext * ec[512 + h];
                float rg = sigm(rpre);
                float zt = sigm(zpre);
                float n  = tanhf(in_ + rg * hn);
                long zi = (long)grow * 256 + h;
                float v = (1.0f - zt) * n + zt * z[zi] + STDF * eps[zi];
                z[zi] = v;
                zh_out[zi] = (_Float16)v;
            }
        }
}

// ------- predict head, BM=32, grid 256: sigm(wo . relu(A@Wd^T+bd) + bo) -----
__global__ __launch_bounds__(256) void predict_head(
    const _Float16* __restrict__ A, int K,
    const _Float16* __restrict__ Wd,     // [256][K]
    const float* __restrict__ bd,
    const float* __restrict__ wo,
    const float* __restrict__ bo,
    float* __restrict__ out, int ostride)
{
    __shared__ char smem[(32 + 256) * 128];
    __shared__ float part[32][4];
    char* Asmem = smem;
    char* Wsmem = smem + 32 * 128;

    const int tid  = threadIdx.x;
    const int wave = tid >> 6;
    const int lane = tid & 63;
    const int bm   = blockIdx.x * 32;
    const int l15  = lane & 15;
    const int l4   = lane >> 4;

    f32x4 acc[2][4];
    #pragma unroll
    for (int a = 0; a < 2; ++a)
        #pragma unroll
        for (int b = 0; b < 4; ++b) { f32x4 zz = {0.f,0.f,0.f,0.f}; acc[a][b] = zz; }

    for (int k0 = 0; k0 < K; k0 += 64) {
        {
            int o   = wave * 1024 + lane * 16;
            int row = o >> 7;
            int c   = ((o >> 4) & 7) ^ (row & 7);
            GLOAD16(A + (long)(bm + row) * K + k0 + c * 8, Asmem + wave * 1024);
        }
        #pragma unroll
        for (int it = 0; it < 8; ++it) {
            int q   = it * 4 + wave;
            int o   = q * 1024 + lane * 16;
            int row = o >> 7;
            int c   = ((o >> 4) & 7) ^ (row & 7);
            GLOAD16(Wd + (long)row * K + k0 + c * 8, Wsmem + q * 1024);
        }
        asm volatile("s_waitcnt vmcnt(0)" ::: "memory");
        __syncthreads();
        #pragma unroll
        for (int ks = 0; ks < 2; ++ks) {
            f16x8 af[2], bf[4];
            #pragma unroll
            for (int mi = 0; mi < 2; ++mi) {
                int row = mi * 16 + l15;
                int c   = (ks * 4 + l4) ^ (row & 7);
                af[mi] = *(const f16x8*)(Asmem + row * 128 + c * 16);
            }
            #pragma unroll
            for (int ni = 0; ni < 4; ++ni) {
                int row = wave * 64 + ni * 16 + l15;
                int c   = (ks * 4 + l4) ^ (row & 7);
                bf[ni] = *(const f16x8*)(Wsmem + row * 128 + c * 16);
            }
            #pragma unroll
            for (int mi = 0; mi < 2; ++mi)
                #pragma unroll
                for (int ni = 0; ni < 4; ++ni)
                    acc[mi][ni] = __builtin_amdgcn_mfma_f32_16x16x32_f16(
                        af[mi], bf[ni], acc[mi][ni], 0, 0, 0);
        }
        __syncthreads();
    }

    float bdv[4], wov[4];
    #pragma unroll
    for (int ni = 0; ni < 4; ++ni) {
        int col = wave * 64 + ni * 16 + l15;
        bdv[ni] = bd[col];
        wov[ni] = wo[col];
    }
    #pragma unroll
    for (int mi = 0; mi < 2; ++mi)
        #pragma unroll
        for (int r = 0; r < 4; ++r) {
            float s = 0.0f;
            #pragma unroll
            for (int ni = 0; ni < 4; ++ni) {
                float v = fmaxf(acc[mi][ni][r] + bdv[ni], 0.0f);
                s = fmaf(v, wov[ni], s);
            }
            #pragma unroll
            for (int off = 1; off < 16; off <<= 1) s += __shfl_xor(s, off, 16);
            if (l15 == 0) part[mi * 16 + l4 * 4 + r][wave] = s;
        }
    __syncthreads();
    if (tid < 32) {
        float u = part[tid][0] + part[tid][1] + part[tid][2] + part[tid][3] + bo[0];
        out[(long)(bm + tid) * ostride] = sigm(u);
    }
}

// ------- decoder head+BCE, BM=32, grid 256 ----------------------------------
__global__ __launch_bounds__(256) void dec_head_bce(
    const _Float16* __restrict__ A,      // zh [B][256]
    const _Float16* __restrict__ Wd,     // [256][256]
    const float* __restrict__ bd,
    const _Float16* __restrict__ Wo,     // [32][256] f16
    const float* __restrict__ bo,        // [32]
    const float* __restrict__ wt,        // [B][32] this layer
    float* __restrict__ bacc)
{
    __shared__ char smem[(32 + 256) * 128];
    __shared__ _Float16 ds[32 * 264];
    __shared__ float part[32][2];
    char* Asmem = smem;
    char* Wsmem = smem + 32 * 128;

    const int tid  = threadIdx.x;
    const int wave = tid >> 6;
    const int lane = tid & 63;
    const int bm   = blockIdx.x * 32;
    const int l15  = lane & 15;
    const int l4   = lane >> 4;

    f32x4 acc[2][4];
    #pragma unroll
    for (int a = 0; a < 2; ++a)
        #pragma unroll
        for (int b = 0; b < 4; ++b) { f32x4 zz = {0.f,0.f,0.f,0.f}; acc[a][b] = zz; }

    for (int k0 = 0; k0 < 256; k0 += 64) {
        {
            int o   = wave * 1024 + lane * 16;
            int row = o >> 7;
            int c   = ((o >> 4) & 7) ^ (row & 7);
            GLOAD16(A + (long)(bm + row) * 256 + k0 + c * 8, Asmem + wave * 1024);
        }
        #pragma unroll
        for (int it = 0; it < 8; ++it) {
            int q   = it * 4 + wave;
            int o   = q * 1024 + lane * 16;
            int row = o >> 7;
            int c   = ((o >> 4) & 7) ^ (row & 7);
            GLOAD16(Wd + (long)row * 256 + k0 + c * 8, Wsmem + q * 1024);
        }
        asm volatile("s_waitcnt vmcnt(0)" ::: "memory");
        __syncthreads();
        #pragma unroll
        for (int ks = 0; ks < 2; ++ks) {
            f16x8 af[2], bf[4];
            #pragma unroll
            for (int mi = 0; mi < 2; ++mi) {
                int row = mi * 16 + l15;
                int c   = (ks * 4 + l4) ^ (row & 7);
                af[mi] = *(const f16x8*)(Asmem + row * 128 + c * 16);
            }
            #pragma unroll
            for (int ni = 0; ni < 4; ++ni) {
                int row = wave * 64 + ni * 16 + l15;
                int c   = (ks * 4 + l4) ^ (row & 7);
                bf[ni] = *(const f16x8*)(Wsmem + row * 128 + c * 16);
            }
            #pragma unroll
            for (int mi = 0; mi < 2; ++mi)
                #pragma unroll
                for (int ni = 0; ni < 4; ++ni)
                    acc[mi][ni] = __builtin_amdgcn_mfma_f32_16x16x32_f16(
                        af[mi], bf[ni], acc[mi][ni], 0, 0, 0);
        }
        __syncthreads();
    }

    // D -> LDS (relu + f16)
    #pragma unroll
    for (int mi = 0; mi < 2; ++mi)
        #pragma unroll
        for (int r = 0; r < 4; ++r) {
            int row = mi * 16 + l4 * 4 + r;
            #pragma unroll
            for (int ni = 0; ni < 4; ++ni) {
                int col = wave * 64 + ni * 16 + l15;
                ds[row * 264 + col] = (_Float16)fmaxf(acc[mi][ni][r] + bd[col], 0.0f);
            }
        }
    __syncthreads();

    // stage 2: u = D @ Wo^T (rows: wave>>1, worker cols: wave&1)
    const int rh = wave >> 1;
    const int ch = wave & 1;
    f32x4 acc2 = {0.f, 0.f, 0.f, 0.f};
    #pragma unroll
    for (int k = 0; k < 8; ++k) {
        f16x8 bf2 = *(const f16x8*)(Wo + (long)(ch * 16 + l15) * 256 + k * 32 + l4 * 8);
        f16x8 af  = *(const f16x8*)(ds + (rh * 16 + l15) * 264 + k * 32 + l4 * 8);
        acc2 = __builtin_amdgcn_mfma_f32_16x16x32_f16(af, bf2, acc2, 0, 0, 0);
    }

    // BCE epilogue
    #pragma unroll
    for (int r = 0; r < 4; ++r) {
        int row = rh * 16 + l4 * 4 + r;
        int w = ch * 16 + l15;
        float u = acc2[r] + bo[w];
        float logp   = fmaxf(logsig(u),  -100.0f);
        float log1mp = fmaxf(logsig(-u), -100.0f);
        float wk = wt[(long)(bm + row) * W_ + w];
        float s = -(wk * logp + (1.0f - wk) * log1mp);
        #pragma unroll
        for (int off = 1; off < 16; off <<= 1) s += __shfl_xor(s, off, 16);
        if (l15 == 0) part[row][ch] = s;
    }
    __syncthreads();
    if (tid < 32) bacc[bm + tid] += part[tid][0] + part[tid][1];
}

// ---------------- workers transpose: [W][B][L] -> [L][B][W] -----------------
__global__ __launch_bounds__(256) void wtrans(
    const float* __restrict__ workers, float* __restrict__ wt)
{
    long idx = (long)blockIdx.x * 256 + threadIdx.x;
    int w = idx & 31;
    long b = idx >> 5;
    const float* src = workers + (w * (long)B_ + b) * L_;
    #pragma unroll
    for (int l = 0; l < L_; ++l)
        wt[((long)l * B_ + b) * W_ + w] = src[l];
}

// ---------------- fused contiguous f32->f16 conversions ---------------------
struct ConvJobs {
    const float* s[10];
    _Float16* d[10];
};
__device__ __constant__ const long CJ_CNT[10] = {
    (long)B_ * X_,            // x
    (long)H_ * X_,            // Wf1
    (long)L_ * G3_ * H_,      // eWhh
    (long)L_ * H_ * H_,       // eWd
    (long)L_ * G3_ * H_,      // dWhh
    (long)L_ * H_ * H_,       // dWd
    (long)L_ * W_ * H_,       // dWo
    (long)X_ * H_,            // Wr
    (long)Z_ * H_,            // Wmu
    (long)Z_ * H_              // Wlv
};
#define CJ_TOTAL 13008896L

__global__ __launch_bounds__(256) void conv_multi(ConvJobs J)
{
    long i8 = ((long)blockIdx.x * 256 + threadIdx.x) * 8;
    if (i8 >= CJ_TOTAL) return;
    long rem = i8; int j = 0;
    #pragma unroll
    for (int k = 0; k < 9; ++k)
        if (rem >= CJ_CNT[k]) { rem -= CJ_CNT[k]; ++j; } else break;
    const float* s = J.s[j] + rem;
    f16x8 o;
    #pragma unroll
    for (int q = 0; q < 8; ++q) o[q] = (_Float16)s[q];
    *(f16x8*)(J.d[j] + rem) = o;
}

// ---------------- strided f32 -> f16 conversion -----------------------------
__global__ __launch_bounds__(256) void conv_f16(
    const float* __restrict__ src, _Float16* __restrict__ dst,
    int Ks, int Kd, long total)
{
    long i = ((long)blockIdx.x * 256 + threadIdx.x) * 8;
    if (i >= total) return;
    long r = i / Kd, k = i - r * Kd;
    const float* s = src + r * Ks + k;
    f16x8 o;
    #pragma unroll
    for (int j = 0; j < 8; ++j) o[j] = (_Float16)s[j];
    *(f16x8*)(dst + i) = o;
}

__global__ __launch_bounds__(256) void extract_col(
    const float* __restrict__ src, float* __restrict__ dst, int Ks, int col, int R)
{
    int i = blockIdx.x * 256 + threadIdx.x;
    if (i < R) dst[i] = src[(long)i * Ks + col];
}

__global__ void stack_bias(const float* __restrict__ a, const float* __restrict__ b,
                           float* __restrict__ o)
{
    int i = threadIdx.x;
    o[i] = (i < 64) ? a[i] : b[i - 64];
}

__global__ __launch_bounds__(256) void zero2_kernel(
    float* __restrict__ z, _Float16* __restrict__ zh, int n)
{
    int i = blockIdx.x * 256 + threadIdx.x;
    if (i < n) { z[i] = 0.0f; zh[i] = (_Float16)0.0f; }
}

__global__ __launch_bounds__(256) void zero_kernel(float* __restrict__ p, int n)
{
    int i = blockIdx.x * 256 + threadIdx.x;
    if (i < n) p[i] = 0.0f;
}

// ---------------- latent elementwise (after muv GEMM) -----------------------
__global__ __launch_bounds__(256) void latent_elem(
    const float* __restrict__ muv,      // [B][128]: mu | lv_raw
    const float* __restrict__ seps,
    float* __restrict__ latent, _Float16* __restrict__ lath,
    float* __restrict__ lq, float* __restrict__ lpz)
{
    int wave = threadIdx.x >> 6, lane = threadIdx.x & 63;
    int b = blockIdx.x * 4 + wave;
    float mu = muv[(long)b * 128 + lane];
    float sp = muv[(long)b * 128 + 64 + lane];
    float lv = (sp > 0.0f) ? (sp + log1pf(expf(-sp))) : log1pf(expf(sp));
    float e  = seps[(long)b * Z_ + lane];
    float lat = mu + expf(0.5f * lv) * e;
    latent[(long)b * Z_ + lane] = lat;
    lath[(long)b * Z_ + lane] = (_Float16)lat;
    float lpz_c = -CC - 0.5f * lat * lat;
    float d = lat - mu;
    float lq_c = -CC - 0.5f * lv - d * d / (2.0f * expf(lv));
    #pragma unroll
    for (int off = 32; off; off >>= 1) {
        lpz_c += __shfl_down(lpz_c, off);
        lq_c  += __shfl_down(lq_c, off);
    }
    if (lane == 0) { lpz[b] = lpz_c; lq[b] = lq_c; }
}

// ---------------- log_p_x from logits ---------------------------------------
__global__ __launch_bounds__(256) void logpx_reduce(
    const float* __restrict__ u, const float* __restrict__ x,
    float* __restrict__ lpx)
{
    int wave = threadIdx.x >> 6, lane = threadIdx.x & 63;
    int b = blockIdx.x * 4 + wave;
    const float* ub = u + (long)b * X_;
    const float* xb = x + (long)b * X_;
    float s = 0.0f;
    #pragma unroll
    for (int i = 0; i < 8; ++i) {
        int k = lane + i * 64;
        s = fmaf(xb[k], logsig(ub[k]), s);
    }
    #pragma unroll
    for (int off = 32; off; off >>= 1) s += __shfl_down(s, off);
    if (lane == 0) lpx[b] = s;
}

// ---------------- KL term ---------------------------------------------------
__global__ __launch_bounds__(256) void kl_kernel(
    const float* __restrict__ tmat, const float* __restrict__ workers,
    float* __restrict__ lkl)
{
    int b = blockIdx.x * 256 + threadIdx.x;
    float wb[L_];
    #pragma unroll
    for (int l = 0; l < L_; ++l) wb[l] = 0.0f;
    for (int w = 0; w < W_; ++w) {
        const float* p = workers + ((long)w * B_ + b) * L_;
        #pragma unroll
        for (int l = 0; l < L_; ++l) wb[l] += p[l];
    }
    float s = 0.0f;
    #pragma unroll
    for (int l = 0; l < L_; ++l) {
        float wbar = wb[l] * (1.0f / 32.0f);
        float tv = tmat[(long)b * L_ + l];
        s += tv * (logf(tv + 1e-6f) - logf(wbar + 1e-6f));
    }
    lkl[b] = s;
}

// ---------------- final reduction ------------------------------------------
__global__ __launch_bounds__(1024) void final_reduce(
    const float* __restrict__ lq, const float* __restrict__ lpz,
    const float* __restrict__ bacc, const float* __restrict__ lpx,
    const float* __restrict__ lkl, float* __restrict__ out)
{
    __shared__ float red[16];
    float s = 0.0f;
    for (int b = threadIdx.x; b < B_; b += 1024)
        s += lq[b] - lpz[b] + bacc[b] - lpx[b] + lkl[b];
    #pragma unroll
    for (int off = 32; off; off >>= 1) s += __shfl_down(s, off);
    int wave = threadIdx.x >> 6, lane = threadIdx.x & 63;
    if (lane == 0) red[wave] = s;
    __syncthreads();
    if (threadIdx.x == 0) {
        float t = 0.0f;
        for (int i = 0; i < 16; ++i) t += red[i];
        out[0] = t / (float)B_;
    }
}

extern "C" void kernel_launch(void* const* d_in, const int* in_sizes, int n_in,
                              void* d_out, int out_size, void* d_ws, size_t ws_size,
                              hipStream_t stream)
{
    const float* x       = (const float*)d_in[0];
    const float* workers = (const float*)d_in[1];
    const float* Wf1     = (const float*)d_in[2];
    const float* bf1     = (const float*)d_in[3];
    const float* Wf2     = (const float*)d_in[4];
    const float* bf2     = (const float*)d_in[5];
    const float* eWih    = (const float*)d_in[6];
    const float* eWhh    = (const float*)d_in[7];
    const float* ebih    = (const float*)d_in[8];
    const float* ebhh    = (const float*)d_in[9];
    const float* eWd     = (const float*)d_in[10];
    const float* ebd     = (const float*)d_in[11];
    const float* eWo     = (const float*)d_in[12];
    const float* ebo     = (const float*)d_in[13];
    const float* Wmu     = (const float*)d_in[14];
    const float* bmu     = (const float*)d_in[15];
    const float* Wlv     = (const float*)d_in[16];
    const float* blv     = (const float*)d_in[17];
    const float* dWih    = (const float*)d_in[18];
    const float* dWhh    = (const float*)d_in[19];
    const float* dbih    = (const float*)d_in[20];
    const float* dbhh    = (const float*)d_in[21];
    const float* dWd     = (const float*)d_in[22];
    const float* dbd     = (const float*)d_in[23];
    const float* dWo     = (const float*)d_in[24];
    const float* dbo     = (const float*)d_in[25];
    const float* Wr      = (const float*)d_in[26];
    const float* br      = (const float*)d_in[27];
    const float* enc_eps = (const float*)d_in[28];
    const float* samp_eps= (const float*)d_in[29];
    const float* dec_eps = (const float*)d_in[30];

    float* t    = (float*)d_out;
    float* loss = t + (long)B_ * L_;

    char* p = (char*)d_ws;
    auto alloc = [&](size_t bytes) {
        char* r = p;
        p += (bytes + 255) & ~(size_t)255;
        return r;
    };
    _Float16* xh    = (_Float16*)alloc((size_t)B_ * X_ * 2);
    _Float16* zha   = (_Float16*)alloc((size_t)B_ * H_ * 2);
    _Float16* zhb   = (_Float16*)alloc((size_t)B_ * H_ * 2);
    _Float16* lath  = (_Float16*)alloc((size_t)B_ * Z_ * 2);
    _Float16* Wf1h  = (_Float16*)alloc((size_t)H_ * X_ * 2);
    _Float16* eWihh = (_Float16*)alloc((size_t)L_ * G3_ * X_ * 2);
    _Float16* eWhhh = (_Float16*)alloc((size_t)L_ * G3_ * H_ * 2);
    _Float16* eWdh  = (_Float16*)alloc((size_t)L_ * H_ * H_ * 2);
    _Float16* dWihh = (_Float16*)alloc((size_t)L_ * G3_ * Z_ * 2);
    _Float16* dWhhh = (_Float16*)alloc((size_t)L_ * G3_ * H_ * 2);
    _Float16* dWdh  = (_Float16*)alloc((size_t)L_ * H_ * H_ * 2);
    _Float16* dWoh  = (_Float16*)alloc((size_t)L_ * W_ * H_ * 2);
    _Float16* Wrh   = (_Float16*)alloc((size_t)X_ * H_ * 2);
    _Float16* Wmlh  = (_Float16*)alloc((size_t)128 * H_ * 2);
    float* bml    = (float*)alloc(128 * 4);
    float* eWihc  = (float*)alloc((size_t)L_ * G3_ * 4);
    float* dWihc  = (float*)alloc((size_t)L_ * G3_ * 4);
    float* z      = (float*)alloc((size_t)B_ * H_ * 4);
    float* dbuf   = (float*)alloc((size_t)B_ * H_ * 4);
    float* latent = (float*)alloc((size_t)B_ * Z_ * 4);
    float* wt     = (float*)alloc((size_t)L_ * B_ * W_ * 4);
    float* logits = (float*)alloc((size_t)B_ * X_ * 4);
    float* lq     = (float*)alloc((size_t)B_ * 4);
    float* lpz    = (float*)alloc((size_t)B_ * 4);
    float* lpx    = (float*)alloc((size_t)B_ * 4);
    float* lkl    = (float*)alloc((size_t)B_ * 4);
    float* bacc   = (float*)alloc((size_t)B_ * 4);

    const dim3 blk(256);
    const int nBH = B_ * H_;
    auto cgrid = [](long total) { return dim3((unsigned)((total / 8 + 255) / 256)); };

    // ---- conversions ----
    ConvJobs J;
    J.s[0] = x;    J.d[0] = xh;
    J.s[1] = Wf1;  J.d[1] = Wf1h;
    J.s[2] = eWhh; J.d[2] = eWhhh;
    J.s[3] = eWd;  J.d[3] = eWdh;
    J.s[4] = dWhh; J.d[4] = dWhhh;
    J.s[5] = dWd;  J.d[5] = dWdh;
    J.s[6] = dWo;  J.d[6] = dWoh;
    J.s[7] = Wr;   J.d[7] = Wrh;
    J.s[8] = Wmu;  J.d[8] = Wmlh;
    J.s[9] = Wlv;  J.d[9] = Wmlh + (long)Z_ * H_;
    conv_multi<<<(CJ_TOTAL / 8 + 255) / 256, blk, 0, stream>>>(J);
    conv_f16<<<cgrid((long)L_ * G3_ * X_), blk, 0, stream>>>(eWih, eWihh, X_ + 1, X_, (long)L_ * G3_ * X_);
    conv_f16<<<cgrid((long)L_ * G3_ * Z_), blk, 0, stream>>>(dWih, dWihh, Z_ + 1, Z_, (long)L_ * G3_ * Z_);
    stack_bias<<<1, 128, 0, stream>>>(bmu, blv, bml);
    extract_col<<<(L_ * G3_ + 255) / 256, blk, 0, stream>>>(eWih, eWihc, X_ + 1, X_, L_ * G3_);
    extract_col<<<(L_ * G3_ + 255) / 256, blk, 0, stream>>>(dWih, dWihc, Z_ + 1, Z_, L_ * G3_);
    wtrans<<<(W_ * B_) / 256, blk, 0, stream>>>(workers, wt);

    // ---- first cell: t[:,0] ----
    zero2_kernel<<<(nBH + 255) / 256, blk, 0, stream>>>(z, zha, nBH);
    predict_head<<<B_ / 32, blk, 0, stream>>>(xh, X_, Wf1h, bf1, Wf2, bf2, t, L_);

    // ---- encoder scan ----
    _Float16* zcur = zha;
    _Float16* znxt = zhb;
    for (int l = 0; l < L_; ++l) {
        gru_fused<1, X_><<<512, blk, 0, stream>>>(
            xh, eWihh + (long)l * G3_ * X_, ebih + (long)l * G3_,
            eWhhh + (long)l * G3_ * H_, ebhh + (long)l * G3_,
            eWihc + (long)l * G3_, t + l, enc_eps + (long)l * nBH,
            zcur, z, znxt);
        _Float16* tmp = zcur; zcur = znxt; znxt = tmp;
        if (l < L_ - 1)
            predict_head<<<B_ / 32, blk, 0, stream>>>(
                zcur, H_, eWdh + (long)l * H_ * H_, ebd + (long)l * H_,
                eWo + (long)l * H_, ebo + l, t + (l + 1), L_);
    }

    // ---- latent: muv GEMM + elementwise ----
    mfma_gemm<64><<<dim3(2, B_ / 128), blk, 0, stream>>>(
        zcur, Wmlh, bml, dbuf, 128, H_, 0);
    latent_elem<<<B_ / 4, blk, 0, stream>>>(dbuf, samp_eps, latent, lath, lq, lpz);

    // ---- decoder scan ----
    zero2_kernel<<<(nBH + 255) / 256, blk, 0, stream>>>(z, zha, nBH);
    zero_kernel<<<(B_ + 255) / 256, blk, 0, stream>>>(bacc, B_);
    zcur = zha; znxt = zhb;
    for (int l = 0; l < L_; ++l) {
        gru_fused<2, Z_><<<512, blk, 0, stream>>>(
            lath, dWihh + (long)l * G3_ * Z_, dbih + (long)l * G3_,
            dWhhh + (long)l * G3_ * H_, dbhh + (long)l * G3_,
            dWihc + (long)l * G3_, t + l, dec_eps + (long)l * nBH,
            zcur, z, znxt);
        _Float16* tmp = zcur; zcur = znxt; znxt = tmp;
        dec_head_bce<<<B_ / 32, blk, 0, stream>>>(
            zcur, dWdh + (long)l * H_ * H_, dbd + (long)l * H_,
            dWoh + (long)l * W_ * H_, dbo + (long)l * W_,
            wt + (long)l * B_ * W_, bacc);
    }

    // ---- recon logits -> log_p_x ----
    mfma_gemm<128><<<dim3(X_ / 128, B_ / 128), blk, 0, stream>>>(
        zcur, Wrh, br, logits, X_, H_, 0);
    logpx_reduce<<<B_ / 4, blk, 0, stream>>>(logits, x, lpx);
    // ---- KL ----
    kl_kernel<<<B_ / 256, blk, 0, stream>>>(t, workers, lkl);
    // ---- final loss ----
    final_reduce<<<1, 1024, 0, stream>>>(lq, lpz, bacc, lpx, lkl, loss);
}

// Round 6
// 1106.647 us; speedup vs baseline: 8.1878x; 1.0584x over previous
//
#include <hip/hip_runtime.h>
#include <hip/hip_bf16.h>
#include <math.h>

#define B_ 8192
#define X_ 512
#define H_ 256
#define Z_ 64
#define L_ 16
#define W_ 32
#define G3_ 768

#define STDF 1.0025031276057952f
#define CC 0.9189385332046727f

typedef _Float16 f16x8 __attribute__((ext_vector_type(8)));
typedef float f32x4 __attribute__((ext_vector_type(4)));

__device__ __forceinline__ float sigm(float x) { return 1.0f / (1.0f + expf(-x)); }
__device__ __forceinline__ float logsig(float u) {
    return (u > 0.0f) ? -log1pf(expf(-u)) : (u - log1pf(expf(u)));
}

#define GLOAD16(gsrc, ldst) \
    __builtin_amdgcn_global_load_lds((const __attribute__((address_space(1))) unsigned int*)(gsrc), \
                                     (__attribute__((address_space(3))) unsigned int*)(ldst), 16, 0, 0)

#define WAITV(N) asm volatile("s_waitcnt vmcnt(" #N ")" ::: "memory")
#define SBAR()  do { __builtin_amdgcn_sched_barrier(0); __builtin_amdgcn_s_barrier(); } while (0)

// ---------------- generic MFMA f16 GEMM (f32 out), BM=128, pipelined --------
template<int BN>
__global__ __launch_bounds__(256) void mfma_gemm(
    const _Float16* __restrict__ A,
    const _Float16* __restrict__ Wt,
    const float* __restrict__ bias,
    float* __restrict__ C, int ldc,
    int K, int act)
{
    constexpr int BM = 128;
    constexpr int WN = BN / 2;
    constexpr int NFR = WN / 16;
    __shared__ char smem[2][(BM + BN) * 128];

    const int tid  = threadIdx.x;
    const int wave = tid >> 6;
    const int lane = tid & 63;
    const int wr   = wave >> 1;
    const int wc   = wave & 1;
    const int bm   = blockIdx.y * BM;
    const int bn   = blockIdx.x * BN;
    const int l15  = lane & 15;
    const int l4   = lane >> 4;

    f32x4 acc[4][NFR];
    #pragma unroll
    for (int a = 0; a < 4; ++a)
        #pragma unroll
        for (int b = 0; b < NFR; ++b) {
            f32x4 zz = {0.f, 0.f, 0.f, 0.f};
            acc[a][b] = zz;
        }

    auto stage = [&](int s, int pb) {
        char* As = smem[pb];
        char* Ws = smem[pb] + BM * 128;
        int k0 = s * 64;
        #pragma unroll
        for (int it = 0; it < 4; ++it) {
            int q   = it * 4 + wave;
            int o   = q * 1024 + lane * 16;
            int row = o >> 7;
            int c   = ((o >> 4) & 7) ^ (row & 7);
            GLOAD16(A + (long)(bm + row) * K + k0 + c * 8, As + q * 1024);
        }
        #pragma unroll
        for (int it = 0; it < BN / 32; ++it) {
            int q   = it * 4 + wave;
            int o   = q * 1024 + lane * 16;
            int row = o >> 7;
            int c   = ((o >> 4) & 7) ^ (row & 7);
            GLOAD16(Wt + (long)(bn + row) * K + k0 + c * 8, Ws + q * 1024);
        }
    };

    const int NT = K >> 6;
    stage(0, 0);
    for (int s = 0; s < NT; ++s) {
        int pb = s & 1;
        if (s + 1 < NT) {
            stage(s + 1, pb ^ 1);
            if constexpr (BN == 128) WAITV(8); else WAITV(6);
        } else WAITV(0);
        SBAR();
        char* As = smem[pb];
        char* Ws = smem[pb] + BM * 128;
        #pragma unroll
        for (int ks = 0; ks < 2; ++ks) {
            f16x8 af[4], bf[NFR];
            #pragma unroll
            for (int mi = 0; mi < 4; ++mi) {
                int row = wr * 64 + mi * 16 + l15;
                int c   = (ks * 4 + l4) ^ (row & 7);
                af[mi] = *(const f16x8*)(As + row * 128 + c * 16);
            }
            #pragma unroll
            for (int ni = 0; ni < NFR; ++ni) {
                int row = wc * WN + ni * 16 + l15;
                int c   = (ks * 4 + l4) ^ (row & 7);
                bf[ni] = *(const f16x8*)(Ws + row * 128 + c * 16);
            }
            #pragma unroll
            for (int mi = 0; mi < 4; ++mi)
                #pragma unroll
                for (int ni = 0; ni < NFR; ++ni)
                    acc[mi][ni] = __builtin_amdgcn_mfma_f32_16x16x32_f16(
                        af[mi], bf[ni], acc[mi][ni], 0, 0, 0);
        }
        SBAR();
    }

    #pragma unroll
    for (int mi = 0; mi < 4; ++mi)
        #pragma unroll
        for (int r = 0; r < 4; ++r) {
            int grow = bm + wr * 64 + mi * 16 + l4 * 4 + r;
            #pragma unroll
            for (int ni = 0; ni < NFR; ++ni) {
                int gcol = bn + wc * WN + ni * 16 + l15;
                float v = acc[mi][ni][r] + bias[gcol];
                if (act) v = fmaxf(v, 0.0f);
                C[(long)grow * ldc + gcol] = v;
            }
        }
}

// ------- fused GRU step, BM=64, grid 512, unified pipelined passes ----------
// MODE 1: enc (t >= .5); MODE 2: dec (t > .5). KX = A2 inner dim.
// FIRST=1: z_prev == 0 -> skip zh@Whh pass entirely, don't read z.
template<int MODE, int KX, int FIRST>
__global__ __launch_bounds__(256) void gru_fused(
    const _Float16* __restrict__ A2,     // [B][KX] (x or latent)
    const _Float16* __restrict__ Wih,    // [768][KX]
    const float* __restrict__ bih,       // [768]
    const _Float16* __restrict__ Whh,    // [768][256]
    const float* __restrict__ bhh,       // [768]
    const float* __restrict__ ec,        // [768]
    const float* __restrict__ tcol,      // stride L_
    const float* __restrict__ eps,       // [B][256]
    const _Float16* __restrict__ zh_in,  // [B][256]
    float* __restrict__ z,               // [B][256] io (write-only if FIRST)
    _Float16* __restrict__ zh_out)       // [B][256]
{
    constexpr int N1 = KX / 64;
    constexpr int NT = N1 + (FIRST ? 0 : 4);
    __shared__ char smem[2][(64 + 192) * 128];

    const int tid  = threadIdx.x;
    const int wave = tid >> 6;
    const int lane = tid & 63;
    const int wr   = wave >> 1;
    const int wc   = wave & 1;
    const int id   = blockIdx.x;
    const int xcd  = id & 7;
    const int wk   = id >> 3;
    const int bm   = (xcd * 16 + (wk >> 2)) * 64;
    const int h0   = (wk & 3) * 64;
    const int l15  = lane & 15;
    const int l4   = lane >> 4;

    f32x4 acc[2][6];   // [mi][r0,r1,z0,z1,hn0,hn1]
    f32x4 accN[2][2];  // [mi][in0,in1]
    #pragma unroll
    for (int a = 0; a < 2; ++a) {
        #pragma unroll
        for (int b = 0; b < 6; ++b) { f32x4 zz = {0.f,0.f,0.f,0.f}; acc[a][b] = zz; }
        #pragma unroll
        for (int b = 0; b < 2; ++b) { f32x4 zz = {0.f,0.f,0.f,0.f}; accN[a][b] = zz; }
    }

    auto stage = [&](int s, int pb) {
        char* As = smem[pb];
        char* Ws = smem[pb] + 64 * 128;
        const _Float16* srcA;
        const _Float16* srcW;
        int KA, k0;
        if (s < N1) { srcA = A2;    srcW = Wih; KA = KX;  k0 = s * 64; }
        else        { srcA = zh_in; srcW = Whh; KA = 256; k0 = (s - N1) * 64; }
        #pragma unroll
        for (int it = 0; it < 2; ++it) {
            int q   = it * 4 + wave;
            int o   = q * 1024 + lane * 16;
            int row = o >> 7;
            int c   = ((o >> 4) & 7) ^ (row & 7);
            GLOAD16(srcA + (long)(bm + row) * KA + k0 + c * 8, As + q * 1024);
        }
        #pragma unroll
        for (int it = 0; it < 6; ++it) {
            int q   = it * 4 + wave;
            int o   = q * 1024 + lane * 16;
            int rr  = o >> 7;
            int c   = ((o >> 4) & 7) ^ (rr & 7);
            int srow = (rr >> 6) * 256 + h0 + (rr & 63);
            GLOAD16(srcW + (long)srow * KA + k0 + c * 8, Ws + q * 1024);
        }
    };

    stage(0, 0);
    for (int s = 0; s < NT; ++s) {
        int pb = s & 1;
        if (s + 1 < NT) { stage(s + 1, pb ^ 1); WAITV(8); }
        else WAITV(0);
        SBAR();
        char* As = smem[pb];
        char* Ws = smem[pb] + 64 * 128;
        bool p1 = (s < N1);
        #pragma unroll
        for (int ks = 0; ks < 2; ++ks) {
            f16x8 af[2], bf[6];
            #pragma unroll
            for (int mi = 0; mi < 2; ++mi) {
                int row = wr * 32 + mi * 16 + l15;
                int c   = (ks * 4 + l4) ^ (row & 7);
                af[mi] = *(const f16x8*)(As + row * 128 + c * 16);
            }
            #pragma unroll
            for (int ni = 0; ni < 6; ++ni) {
                int rr = (ni >> 1) * 64 + wc * 32 + (ni & 1) * 16 + l15;
                int c  = (ks * 4 + l4) ^ (rr & 7);
                bf[ni] = *(const f16x8*)(Ws + rr * 128 + c * 16);
            }
            if (p1) {
                #pragma unroll
                for (int mi = 0; mi < 2; ++mi) {
                    #pragma unroll
                    for (int ni = 0; ni < 4; ++ni)
                        acc[mi][ni] = __builtin_amdgcn_mfma_f32_16x16x32_f16(
                            af[mi], bf[ni], acc[mi][ni], 0, 0, 0);
                    #pragma unroll
                    for (int ni = 4; ni < 6; ++ni)
                        accN[mi][ni - 4] = __builtin_amdgcn_mfma_f32_16x16x32_f16(
                            af[mi], bf[ni], accN[mi][ni - 4], 0, 0, 0);
                }
            } else {
                #pragma unroll
                for (int mi = 0; mi < 2; ++mi)
                    #pragma unroll
                    for (int ni = 0; ni < 6; ++ni)
                        acc[mi][ni] = __builtin_amdgcn_mfma_f32_16x16x32_f16(
                            af[mi], bf[ni], acc[mi][ni], 0, 0, 0);
            }
        }
        SBAR();
    }

    // ---- GRU combine epilogue ----
    #pragma unroll
    for (int mi = 0; mi < 2; ++mi)
        #pragma unroll
        for (int r = 0; r < 4; ++r) {
            int grow = bm + wr * 32 + mi * 16 + l4 * 4 + r;
            float tv = tcol[(long)grow * L_];
            float ext = (MODE == 1) ? (tv >= 0.5f ? 1.0f : 0.0f)
                                    : (tv >  0.5f ? 1.0f : 0.0f);
            #pragma unroll
            for (int hb = 0; hb < 2; ++hb) {
                int h = h0 + wc * 32 + hb * 16 + l15;
                float rpre = acc[mi][hb][r]     + bih[h]       + bhh[h]       + ext * ec[h];
                float zpre = acc[mi][2 + hb][r] + bih[256 + h] + bhh[256 + h] + ext * ec[256 + h];
                float hn   = acc[mi][4 + hb][r] + bhh[512 + h];
                float in_  = accN[mi][hb][r]    + bih[512 + h] + ext * ec[512 + h];
                float rg = sigm(rpre);
                float zt = sigm(zpre);
                float n  = tanhf(in_ + rg * hn);
                long zi = (long)grow * 256 + h;
                float zold = FIRST ? 0.0f : z[zi];
                float v = (1.0f - zt) * n + zt * zold + STDF * eps[zi];
                z[zi] = v;
                zh_out[zi] = (_Float16)v;
            }
        }
}

// ------- predict head, BM=32, grid 256, pipelined ---------------------------
template<int K>
__global__ __launch_bounds__(256) void predict_head(
    const _Float16* __restrict__ A,
    const _Float16* __restrict__ Wd,     // [256][K]
    const float* __restrict__ bd,
    const float* __restrict__ wo,
    const float* __restrict__ bo,
    float* __restrict__ out, int ostride)
{
    constexpr int NT = K / 64;
    __shared__ char smem[2][(32 + 256) * 128];
    __shared__ float part[32][4];

    const int tid  = threadIdx.x;
    const int wave = tid >> 6;
    const int lane = tid & 63;
    const int bm   = blockIdx.x * 32;
    const int l15  = lane & 15;
    const int l4   = lane >> 4;

    f32x4 acc[2][4];
    #pragma unroll
    for (int a = 0; a < 2; ++a)
        #pragma unroll
        for (int b = 0; b < 4; ++b) { f32x4 zz = {0.f,0.f,0.f,0.f}; acc[a][b] = zz; }

    auto stage = [&](int s, int pb) {
        char* As = smem[pb];
        char* Ws = smem[pb] + 32 * 128;
        int k0 = s * 64;
        {
            int o   = wave * 1024 + lane * 16;
            int row = o >> 7;
            int c   = ((o >> 4) & 7) ^ (row & 7);
            GLOAD16(A + (long)(bm + row) * K + k0 + c * 8, As + wave * 1024);
        }
        #pragma unroll
        for (int it = 0; it < 8; ++it) {
            int q   = it * 4 + wave;
            int o   = q * 1024 + lane * 16;
            int row = o >> 7;
            int c   = ((o >> 4) & 7) ^ (row & 7);
            GLOAD16(Wd + (long)row * K + k0 + c * 8, Ws + q * 1024);
        }
    };

    stage(0, 0);
    for (int s = 0; s < NT; ++s) {
        int pb = s & 1;
        if (s + 1 < NT) { stage(s + 1, pb ^ 1); WAITV(9); }
        else WAITV(0);
        SBAR();
        char* As = smem[pb];
        char* Ws = smem[pb] + 32 * 128;
        #pragma unroll
        for (int ks = 0; ks < 2; ++ks) {
            f16x8 af[2], bf[4];
            #pragma unroll
            for (int mi = 0; mi < 2; ++mi) {
                int row = mi * 16 + l15;
                int c   = (ks * 4 + l4) ^ (row & 7);
                af[mi] = *(const f16x8*)(As + row * 128 + c * 16);
            }
            #pragma unroll
            for (int ni = 0; ni < 4; ++ni) {
                int row = wave * 64 + ni * 16 + l15;
                int c   = (ks * 4 + l4) ^ (row & 7);
                bf[ni] = *(const f16x8*)(Ws + row * 128 + c * 16);
            }
            #pragma unroll
            for (int mi = 0; mi < 2; ++mi)
                #pragma unroll
                for (int ni = 0; ni < 4; ++ni)
                    acc[mi][ni] = __builtin_amdgcn_mfma_f32_16x16x32_f16(
                        af[mi], bf[ni], acc[mi][ni], 0, 0, 0);
        }
        SBAR();
    }

    float bdv[4], wov[4];
    #pragma unroll
    for (int ni = 0; ni < 4; ++ni) {
        int col = wave * 64 + ni * 16 + l15;
        bdv[ni] = bd[col];
        wov[ni] = wo[col];
    }
    #pragma unroll
    for (int mi = 0; mi < 2; ++mi)
        #pragma unroll
        for (int r = 0; r < 4; ++r) {
            float s = 0.0f;
            #pragma unroll
            for (int ni = 0; ni < 4; ++ni) {
                float v = fmaxf(acc[mi][ni][r] + bdv[ni], 0.0f);
                s = fmaf(v, wov[ni], s);
            }
            #pragma unroll
            for (int off = 1; off < 16; off <<= 1) s += __shfl_xor(s, off, 16);
            if (l15 == 0) part[mi * 16 + l4 * 4 + r][wave] = s;
        }
    __syncthreads();
    if (tid < 32) {
        float u = part[tid][0] + part[tid][1] + part[tid][2] + part[tid][3] + bo[0];
        out[(long)(bm + tid) * ostride] = sigm(u);
    }
}

// ------- decoder head+BCE, BM=32, grid 256, pipelined -----------------------
__global__ __launch_bounds__(256) void dec_head_bce(
    const _Float16* __restrict__ A,      // zh [B][256]
    const _Float16* __restrict__ Wd,     // [256][256]
    const float* __restrict__ bd,
    const _Float16* __restrict__ Wo,     // [32][256] f16
    const float* __restrict__ bo,        // [32]
    const float* __restrict__ wt,        // [B][32] this layer
    float* __restrict__ bacc)
{
    constexpr int NT = 4;
    __shared__ char smem[2][(32 + 256) * 128];
    __shared__ _Float16 ds[32 * 264];
    __shared__ float part[32][2];

    const int tid  = threadIdx.x;
    const int wave = tid >> 6;
    const int lane = tid & 63;
    const int bm   = blockIdx.x * 32;
    const int l15  = lane & 15;
    const int l4   = lane >> 4;

    f32x4 acc[2][4];
    #pragma unroll
    for (int a = 0; a < 2; ++a)
        #pragma unroll
        for (int b = 0; b < 4; ++b) { f32x4 zz = {0.f,0.f,0.f,0.f}; acc[a][b] = zz; }

    auto stage = [&](int s, int pb) {
        char* As = smem[pb];
        char* Ws = smem[pb] + 32 * 128;
        int k0 = s * 64;
        {
            int o   = wave * 1024 + lane * 16;
            int row = o >> 7;
            int c   = ((o >> 4) & 7) ^ (row & 7);
            GLOAD16(A + (long)(bm + row) * 256 + k0 + c * 8, As + wave * 1024);
        }
        #pragma unroll
        for (int it = 0; it < 8; ++it) {
            int q   = it * 4 + wave;
            int o   = q * 1024 + lane * 16;
            int row = o >> 7;
            int c   = ((o >> 4) & 7) ^ (row & 7);
            GLOAD16(Wd + (long)row * 256 + k0 + c * 8, Ws + q * 1024);
        }
    };

    stage(0, 0);
    for (int s = 0; s < NT; ++s) {
        int pb = s & 1;
        if (s + 1 < NT) { stage(s + 1, pb ^ 1); WAITV(9); }
        else WAITV(0);
        SBAR();
        char* As = smem[pb];
        char* Ws = smem[pb] + 32 * 128;
        #pragma unroll
        for (int ks = 0; ks < 2; ++ks) {
            f16x8 af[2], bf[4];
            #pragma unroll
            for (int mi = 0; mi < 2; ++mi) {
                int row = mi * 16 + l15;
                int c   = (ks * 4 + l4) ^ (row & 7);
                af[mi] = *(const f16x8*)(As + row * 128 + c * 16);
            }
            #pragma unroll
            for (int ni = 0; ni < 4; ++ni) {
                int row = wave * 64 + ni * 16 + l15;
                int c   = (ks * 4 + l4) ^ (row & 7);
                bf[ni] = *(const f16x8*)(Ws + row * 128 + c * 16);
            }
            #pragma unroll
            for (int mi = 0; mi < 2; ++mi)
                #pragma unroll
                for (int ni = 0; ni < 4; ++ni)
                    acc[mi][ni] = __builtin_amdgcn_mfma_f32_16x16x32_f16(
                        af[mi], bf[ni], acc[mi][ni], 0, 0, 0);
        }
        SBAR();
    }

    // D -> LDS (relu + f16)
    #pragma unroll
    for (int mi = 0; mi < 2; ++mi)
        #pragma unroll
        for (int r = 0; r < 4; ++r) {
            int row = mi * 16 + l4 * 4 + r;
            #pragma unroll
            for (int ni = 0; ni < 4; ++ni) {
                int col = wave * 64 + ni * 16 + l15;
                ds[row * 264 + col] = (_Float16)fmaxf(acc[mi][ni][r] + bd[col], 0.0f);
            }
        }
    __syncthreads();

    // stage 2: u = D @ Wo^T (rows: wave>>1, worker cols: wave&1)
    const int rh = wave >> 1;
    const int ch = wave & 1;
    f32x4 acc2 = {0.f, 0.f, 0.f, 0.f};
    #pragma unroll
    for (int k = 0; k < 8; ++k) {
        f16x8 bf2 = *(const f16x8*)(Wo + (long)(ch * 16 + l15) * 256 + k * 32 + l4 * 8);
        f16x8 af  = *(const f16x8*)(ds + (rh * 16 + l15) * 264 + k * 32 + l4 * 8);
        acc2 = __builtin_amdgcn_mfma_f32_16x16x32_f16(af, bf2, acc2, 0, 0, 0);
    }

    // BCE epilogue
    #pragma unroll
    for (int r = 0; r < 4; ++r) {
        int row = rh * 16 + l4 * 4 + r;
        int w = ch * 16 + l15;
        float u = acc2[r] + bo[w];
        float logp   = fmaxf(logsig(u),  -100.0f);
        float log1mp = fmaxf(logsig(-u), -100.0f);
        float wk = wt[(long)(bm + row) * W_ + w];
        float s = -(wk * logp + (1.0f - wk) * log1mp);
        #pragma unroll
        for (int off = 1; off < 16; off <<= 1) s += __shfl_xor(s, off, 16);
        if (l15 == 0) part[row][ch] = s;
    }
    __syncthreads();
    if (tid < 32) bacc[bm + tid] += part[tid][0] + part[tid][1];
}

// -------- workers transpose [W][B][L] -> [L][B][W]; also zeroes bacc --------
__global__ __launch_bounds__(256) void wtrans(
    const float* __restrict__ workers, float* __restrict__ wt,
    float* __restrict__ bacc)
{
    long idx = (long)blockIdx.x * 256 + threadIdx.x;
    int w = idx & 31;
    long b = idx >> 5;
    const float* src = workers + (w * (long)B_ + b) * L_;
    #pragma unroll
    for (int l = 0; l < L_; ++l)
        wt[((long)l * B_ + b) * W_ + w] = src[l];
    if (w == 0) bacc[b] = 0.0f;
}

// ---------------- fused contiguous f32->f16 conversions ---------------------
struct ConvJobs {
    const float* s[10];
    _Float16* d[10];
};
__device__ __constant__ const long CJ_CNT[10] = {
    (long)B_ * X_,            // x
    (long)H_ * X_,            // Wf1
    (long)L_ * G3_ * H_,      // eWhh
    (long)L_ * H_ * H_,       // eWd
    (long)L_ * G3_ * H_,      // dWhh
    (long)L_ * H_ * H_,       // dWd
    (long)L_ * W_ * H_,       // dWo
    (long)X_ * H_,            // Wr
    (long)Z_ * H_,            // Wmu
    (long)Z_ * H_              // Wlv
};
#define CJ_TOTAL 13008896L

__global__ __launch_bounds__(256) void conv_multi(ConvJobs J)
{
    long i8 = ((long)blockIdx.x * 256 + threadIdx.x) * 8;
    if (i8 >= CJ_TOTAL) return;
    long rem = i8; int j = 0;
    #pragma unroll
    for (int k = 0; k < 9; ++k)
        if (rem >= CJ_CNT[k]) { rem -= CJ_CNT[k]; ++j; } else break;
    const float* s = J.s[j] + rem;
    f16x8 o;
    #pragma unroll
    for (int q = 0; q < 8; ++q) o[q] = (_Float16)s[q];
    *(f16x8*)(J.d[j] + rem) = o;
}

// ---------------- strided f32 -> f16 conversion -----------------------------
__global__ __launch_bounds__(256) void conv_f16(
    const float* __restrict__ src, _Float16* __restrict__ dst,
    int Ks, int Kd, long total)
{
    long i = ((long)blockIdx.x * 256 + threadIdx.x) * 8;
    if (i >= total) return;
    long r = i / Kd, k = i - r * Kd;
    const float* s = src + r * Ks + k;
    f16x8 o;
    #pragma unroll
    for (int j = 0; j < 8; ++j) o[j] = (_Float16)s[j];
    *(f16x8*)(dst + i) = o;
}

__global__ __launch_bounds__(256) void extract_col(
    const float* __restrict__ src, float* __restrict__ dst, int Ks, int col, int R)
{
    int i = blockIdx.x * 256 + threadIdx.x;
    if (i < R) dst[i] = src[(long)i * Ks + col];
}

__global__ void stack_bias(const float* __restrict__ a, const float* __restrict__ b,
                           float* __restrict__ o)
{
    int i = threadIdx.x;
    o[i] = (i < 64) ? a[i] : b[i - 64];
}

// ---------------- latent elementwise (after muv GEMM) -----------------------
__global__ __launch_bounds__(256) void latent_elem(
    const float* __restrict__ muv,      // [B][128]: mu | lv_raw
    const float* __restrict__ seps,
    float* __restrict__ latent, _Float16* __restrict__ lath,
    float* __restrict__ lq, float* __restrict__ lpz)
{
    int wave = threadIdx.x >> 6, lane = threadIdx.x & 63;
    int b = blockIdx.x * 4 + wave;
    float mu = muv[(long)b * 128 + lane];
    float sp = muv[(long)b * 128 + 64 + lane];
    float lv = (sp > 0.0f) ? (sp + log1pf(expf(-sp))) : log1pf(expf(sp));
    float e  = seps[(long)b * Z_ + lane];
    float lat = mu + expf(0.5f * lv) * e;
    latent[(long)b * Z_ + lane] = lat;
    lath[(long)b * Z_ + lane] = (_Float16)lat;
    float lpz_c = -CC - 0.5f * lat * lat;
    float d = lat - mu;
    float lq_c = -CC - 0.5f * lv - d * d / (2.0f * expf(lv));
    #pragma unroll
    for (int off = 32; off; off >>= 1) {
        lpz_c += __shfl_down(lpz_c, off);
        lq_c  += __shfl_down(lq_c, off);
    }
    if (lane == 0) { lpz[b] = lpz_c; lq[b] = lq_c; }
}

// ---------------- log_p_x from logits ---------------------------------------
__global__ __launch_bounds__(256) void logpx_reduce(
    const float* __restrict__ u, const float* __restrict__ x,
    float* __restrict__ lpx)
{
    int wave = threadIdx.x >> 6, lane = threadIdx.x & 63;
    int b = blockIdx.x * 4 + wave;
    const float* ub = u + (long)b * X_;
    const float* xb = x + (long)b * X_;
    float s = 0.0f;
    #pragma unroll
    for (int i = 0; i < 8; ++i) {
        int k = lane + i * 64;
        s = fmaf(xb[k], logsig(ub[k]), s);
    }
    #pragma unroll
    for (int off = 32; off; off >>= 1) s += __shfl_down(s, off);
    if (lane == 0) lpx[b] = s;
}

// ---------------- KL term ---------------------------------------------------
__global__ __launch_bounds__(256) void kl_kernel(
    const float* __restrict__ tmat, const float* __restrict__ workers,
    float* __restrict__ lkl)
{
    int b = blockIdx.x * 256 + threadIdx.x;
    float wb[L_];
    #pragma unroll
    for (int l = 0; l < L_; ++l) wb[l] = 0.0f;
    for (int w = 0; w < W_; ++w) {
        const float* p = workers + ((long)w * B_ + b) * L_;
        #pragma unroll
        for (int l = 0; l < L_; ++l) wb[l] += p[l];
    }
    float s = 0.0f;
    #pragma unroll
    for (int l = 0; l < L_; ++l) {
        float wbar = wb[l] * (1.0f / 32.0f);
        float tv = tmat[(long)b * L_ + l];
        s += tv * (logf(tv + 1e-6f) - logf(wbar + 1e-6f));
    }
    lkl[b] = s;
}

// ---------------- final reduction ------------------------------------------
__global__ __launch_bounds__(1024) void final_reduce(
    const float* __restrict__ lq, const float* __restrict__ lpz,
    const float* __restrict__ bacc, const float* __restrict__ lpx,
    const float* __restrict__ lkl, float* __restrict__ out)
{
    __shared__ float red[16];
    float s = 0.0f;
    for (int b = threadIdx.x; b < B_; b += 1024)
        s += lq[b] - lpz[b] + bacc[b] - lpx[b] + lkl[b];
    #pragma unroll
    for (int off = 32; off; off >>= 1) s += __shfl_down(s, off);
    int wave = threadIdx.x >> 6, lane = threadIdx.x & 63;
    if (lane == 0) red[wave] = s;
    __syncthreads();
    if (threadIdx.x == 0) {
        float t = 0.0f;
        for (int i = 0; i < 16; ++i) t += red[i];
        out[0] = t / (float)B_;
    }
}

extern "C" void kernel_launch(void* const* d_in, const int* in_sizes, int n_in,
                              void* d_out, int out_size, void* d_ws, size_t ws_size,
                              hipStream_t stream)
{
    const float* x       = (const float*)d_in[0];
    const float* workers = (const float*)d_in[1];
    const float* Wf1     = (const float*)d_in[2];
    const float* bf1     = (const float*)d_in[3];
    const float* Wf2     = (const float*)d_in[4];
    const float* bf2     = (const float*)d_in[5];
    const float* eWih    = (const float*)d_in[6];
    const float* eWhh    = (const float*)d_in[7];
    const float* ebih    = (const float*)d_in[8];
    const float* ebhh    = (const float*)d_in[9];
    const float* eWd     = (const float*)d_in[10];
    const float* ebd     = (const float*)d_in[11];
    const float* eWo     = (const float*)d_in[12];
    const float* ebo     = (const float*)d_in[13];
    const float* Wmu     = (const float*)d_in[14];
    const float* bmu     = (const float*)d_in[15];
    const float* Wlv     = (const float*)d_in[16];
    const float* blv     = (const float*)d_in[17];
    const float* dWih    = (const float*)d_in[18];
    const float* dWhh    = (const float*)d_in[19];
    const float* dbih    = (const float*)d_in[20];
    const float* dbhh    = (const float*)d_in[21];
    const float* dWd     = (const float*)d_in[22];
    const float* dbd     = (const float*)d_in[23];
    const float* dWo     = (const float*)d_in[24];
    const float* dbo     = (const float*)d_in[25];
    const float* Wr      = (const float*)d_in[26];
    const float* br      = (const float*)d_in[27];
    const float* enc_eps = (const float*)d_in[28];
    const float* samp_eps= (const float*)d_in[29];
    const float* dec_eps = (const float*)d_in[30];

    float* t    = (float*)d_out;
    float* loss = t + (long)B_ * L_;

    char* p = (char*)d_ws;
    auto alloc = [&](size_t bytes) {
        char* r = p;
        p += (bytes + 255) & ~(size_t)255;
        return r;
    };
    _Float16* xh    = (_Float16*)alloc((size_t)B_ * X_ * 2);
    _Float16* zha   = (_Float16*)alloc((size_t)B_ * H_ * 2);
    _Float16* zhb   = (_Float16*)alloc((size_t)B_ * H_ * 2);
    _Float16* lath  = (_Float16*)alloc((size_t)B_ * Z_ * 2);
    _Float16* Wf1h  = (_Float16*)alloc((size_t)H_ * X_ * 2);
    _Float16* eWihh = (_Float16*)alloc((size_t)L_ * G3_ * X_ * 2);
    _Float16* eWhhh = (_Float16*)alloc((size_t)L_ * G3_ * H_ * 2);
    _Float16* eWdh  = (_Float16*)alloc((size_t)L_ * H_ * H_ * 2);
    _Float16* dWihh = (_Float16*)alloc((size_t)L_ * G3_ * Z_ * 2);
    _Float16* dWhhh = (_Float16*)alloc((size_t)L_ * G3_ * H_ * 2);
    _Float16* dWdh  = (_Float16*)alloc((size_t)L_ * H_ * H_ * 2);
    _Float16* dWoh  = (_Float16*)alloc((size_t)L_ * W_ * H_ * 2);
    _Float16* Wrh   = (_Float16*)alloc((size_t)X_ * H_ * 2);
    _Float16* Wmlh  = (_Float16*)alloc((size_t)128 * H_ * 2);
    float* bml    = (float*)alloc(128 * 4);
    float* eWihc  = (float*)alloc((size_t)L_ * G3_ * 4);
    float* dWihc  = (float*)alloc((size_t)L_ * G3_ * 4);
    float* z      = (float*)alloc((size_t)B_ * H_ * 4);
    float* dbuf   = (float*)alloc((size_t)B_ * H_ * 4);
    float* latent = (float*)alloc((size_t)B_ * Z_ * 4);
    float* wt     = (float*)alloc((size_t)L_ * B_ * W_ * 4);
    float* logits = (float*)alloc((size_t)B_ * X_ * 4);
    float* lq     = (float*)alloc((size_t)B_ * 4);
    float* lpz    = (float*)alloc((size_t)B_ * 4);
    float* lpx    = (float*)alloc((size_t)B_ * 4);
    float* lkl    = (float*)alloc((size_t)B_ * 4);
    float* bacc   = (float*)alloc((size_t)B_ * 4);

    const dim3 blk(256);
    const int nBH = B_ * H_;
    auto cgrid = [](long total) { return dim3((unsigned)((total / 8 + 255) / 256)); };

    // ---- conversions ----
    ConvJobs J;
    J.s[0] = x;    J.d[0] = xh;
    J.s[1] = Wf1;  J.d[1] = Wf1h;
    J.s[2] = eWhh; J.d[2] = eWhhh;
    J.s[3] = eWd;  J.d[3] = eWdh;
    J.s[4] = dWhh; J.d[4] = dWhhh;
    J.s[5] = dWd;  J.d[5] = dWdh;
    J.s[6] = dWo;  J.d[6] = dWoh;
    J.s[7] = Wr;   J.d[7] = Wrh;
    J.s[8] = Wmu;  J.d[8] = Wmlh;
    J.s[9] = Wlv;  J.d[9] = Wmlh + (long)Z_ * H_;
    conv_multi<<<(CJ_TOTAL / 8 + 255) / 256, blk, 0, stream>>>(J);
    conv_f16<<<cgrid((long)L_ * G3_ * X_), blk, 0, stream>>>(eWih, eWihh, X_ + 1, X_, (long)L_ * G3_ * X_);
    conv_f16<<<cgrid((long)L_ * G3_ * Z_), blk, 0, stream>>>(dWih, dWihh, Z_ + 1, Z_, (long)L_ * G3_ * Z_);
    stack_bias<<<1, 128, 0, stream>>>(bmu, blv, bml);
    extract_col<<<(L_ * G3_ + 255) / 256, blk, 0, stream>>>(eWih, eWihc, X_ + 1, X_, L_ * G3_);
    extract_col<<<(L_ * G3_ + 255) / 256, blk, 0, stream>>>(dWih, dWihc, Z_ + 1, Z_, L_ * G3_);
    wtrans<<<(W_ * B_) / 256, blk, 0, stream>>>(workers, wt, bacc);

    // ---- first cell: t[:,0] ----
    predict_head<X_><<<B_ / 32, blk, 0, stream>>>(xh, Wf1h, bf1, Wf2, bf2, t, L_);

    // ---- encoder scan ----
    _Float16* zcur = zha;
    _Float16* znxt = zhb;
    for (int l = 0; l < L_; ++l) {
        if (l == 0)
            gru_fused<1, X_, 1><<<512, blk, 0, stream>>>(
                xh, eWihh, ebih, eWhhh, ebhh, eWihc, t, enc_eps, zcur, z, znxt);
        else
            gru_fused<1, X_, 0><<<512, blk, 0, stream>>>(
                xh, eWihh + (long)l * G3_ * X_, ebih + (long)l * G3_,
                eWhhh + (long)l * G3_ * H_, ebhh + (long)l * G3_,
                eWihc + (long)l * G3_, t + l, enc_eps + (long)l * nBH,
                zcur, z, znxt);
        _Float16* tmp = zcur; zcur = znxt; znxt = tmp;
        if (l < L_ - 1)
            predict_head<H_><<<B_ / 32, blk, 0, stream>>>(
                zcur, eWdh + (long)l * H_ * H_, ebd + (long)l * H_,
                eWo + (long)l * H_, ebo + l, t + (l + 1), L_);
    }

    // ---- latent: muv GEMM + elementwise ----
    mfma_gemm<64><<<dim3(2, B_ / 128), blk, 0, stream>>>(
        zcur, Wmlh, bml, dbuf, 128, H_, 0);
    latent_elem<<<B_ / 4, blk, 0, stream>>>(dbuf, samp_eps, latent, lath, lq, lpz);

    // ---- decoder scan ----
    zcur = zha; znxt = zhb;
    for (int l = 0; l < L_; ++l) {
        if (l == 0)
            gru_fused<2, Z_, 1><<<512, blk, 0, stream>>>(
                lath, dWihh, dbih, dWhhh, dbhh, dWihc, t, dec_eps, zcur, z, znxt);
        else
            gru_fused<2, Z_, 0><<<512, blk, 0, stream>>>(
                lath, dWihh + (long)l * G3_ * Z_, dbih + (long)l * G3_,
                dWhhh + (long)l * G3_ * H_, dbhh + (long)l * G3_,
                dWihc + (long)l * G3_, t + l, dec_eps + (long)l * nBH,
                zcur, z, znxt);
        _Float16* tmp = zcur; zcur = znxt; znxt = tmp;
        dec_head_bce<<<B_ / 32, blk, 0, stream>>>(
            zcur, dWdh + (long)l * H_ * H_, dbd + (long)l * H_,
            dWoh + (long)l * W_ * H_, dbo + (long)l * W_,
            wt + (long)l * B_ * W_, bacc);
    }

    // ---- recon logits -> log_p_x ----
    mfma_gemm<128><<<dim3(X_ / 128, B_ / 128), blk, 0, stream>>>(
        zcur, Wrh, br, logits, X_, H_, 0);
    logpx_reduce<<<B_ / 4, blk, 0, stream>>>(logits, x, lpx);
    // ---- KL ----
    kl_kernel<<<B_ / 256, blk, 0, stream>>>(t, workers, lkl);
    // ---- final loss ----
    final_reduce<<<1, 1024, 0, stream>>>(lq, lpz, bacc, lpx, lkl, loss);
}